// Round 1
// baseline (238.483 us; speedup 1.0000x reference)
//
#include <hip/hip_runtime.h>
#include <hip/hip_bf16.h>

typedef __attribute__((ext_vector_type(8))) short short8_t;
typedef __attribute__((ext_vector_type(4))) float f32x4;
using bf16 = __hip_bfloat16;

#define MFMA_BF16(A, B, C) __builtin_amdgcn_mfma_f32_16x16x32_bf16((A), (B), (C), 0, 0, 0)

#define GLD_LDS16(g, l)                                                        \
  __builtin_amdgcn_global_load_lds(                                           \
      (const __attribute__((address_space(1))) unsigned int*)(const void*)(g),\
      (__attribute__((address_space(3))) unsigned int*)(void*)(l), 16, 0, 0)

__device__ __forceinline__ float bits2f(short s) {
  union { unsigned int u; float f; } c;
  c.u = ((unsigned int)(unsigned short)s) << 16;
  return c.f;
}
__device__ __forceinline__ short f2bits(float f) {
  bf16 h = __float2bfloat16(f);
  return *reinterpret_cast<short*>(&h);
}

// ---------------- fp32 -> bf16 convert (vectorized) ----------------
__global__ __launch_bounds__(256) void cvt_f32_bf16(const float* __restrict__ in,
                                                    short* __restrict__ out, int n) {
  int i = (blockIdx.x * 256 + threadIdx.x) * 4;
  if (i >= n) return;
  float4 v = *reinterpret_cast<const float4*>(in + i);
  short4 o;
  o.x = f2bits(v.x); o.y = f2bits(v.y); o.z = f2bits(v.z); o.w = f2bits(v.w);
  *reinterpret_cast<short4*>(out + i) = o;
}

// ---------------- bf16 B^T GEMM: C[m][n] = sum_k A[m][k] * Bt[n][k] ----------------
// 128x128 tile, BK=32, 4 waves (2x2), global_load_lds width-16 staging (m97 structure).
template <int STORE_BF16>
__global__ __launch_bounds__(256) void gemm_bt(const short* __restrict__ A,
                                               const short* __restrict__ Bt,
                                               void* __restrict__ C, int M, int N, int K) {
  __shared__ __align__(16) short As[128 * 32];
  __shared__ __align__(16) short Bs[128 * 32];
  const int m0 = blockIdx.y * 128, n0 = blockIdx.x * 128;
  const int tid = threadIdx.x, wave = tid >> 6, lane = tid & 63;
  const int wr = wave >> 1, wc = wave & 1;
  const int rr = lane & 15, g = lane >> 4;

  f32x4 acc[4][4];
#pragma unroll
  for (int mi = 0; mi < 4; ++mi)
#pragma unroll
    for (int ni = 0; ni < 4; ++ni) acc[mi][ni] = (f32x4){0.f, 0.f, 0.f, 0.f};

  const int srow = wave * 32 + (lane >> 2);  // +16 for second chunk
  const int scol = (lane & 3) * 8;
  const short* Abase = A + (size_t)(m0 + srow) * K + scol;
  const short* Bbase = Bt + (size_t)(n0 + srow) * K + scol;

  for (int k0 = 0; k0 < K; k0 += 32) {
    if (k0) __syncthreads();
    GLD_LDS16(Abase + k0, &As[wave * 1024]);
    GLD_LDS16(Abase + 16 * (size_t)K + k0, &As[wave * 1024 + 512]);
    GLD_LDS16(Bbase + k0, &Bs[wave * 1024]);
    GLD_LDS16(Bbase + 16 * (size_t)K + k0, &Bs[wave * 1024 + 512]);
    __syncthreads();

    short8_t af[4], bfv[4];
#pragma unroll
    for (int mi = 0; mi < 4; ++mi)
      af[mi] = *reinterpret_cast<const short8_t*>(&As[(wr * 64 + mi * 16 + rr) * 32 + g * 8]);
#pragma unroll
    for (int ni = 0; ni < 4; ++ni)
      bfv[ni] = *reinterpret_cast<const short8_t*>(&Bs[(wc * 64 + ni * 16 + rr) * 32 + g * 8]);
#pragma unroll
    for (int mi = 0; mi < 4; ++mi)
#pragma unroll
      for (int ni = 0; ni < 4; ++ni)
        acc[mi][ni] = MFMA_BF16(af[mi], bfv[ni], acc[mi][ni]);
  }

#pragma unroll
  for (int mi = 0; mi < 4; ++mi)
#pragma unroll
    for (int ni = 0; ni < 4; ++ni) {
      const int row = m0 + wr * 64 + mi * 16 + g * 4;
      const int col = n0 + wc * 64 + ni * 16 + rr;
#pragma unroll
      for (int j = 0; j < 4; ++j) {
        float v = acc[mi][ni][j];
        if (STORE_BF16)
          reinterpret_cast<short*>(C)[(size_t)(row + j) * N + col] = f2bits(v);
        else
          reinterpret_cast<float*>(C)[(size_t)(row + j) * N + col] = v;
      }
    }
}

// ---------------- RoPE + RMS for q and k ----------------
// qkv: (B*T, 3072) bf16; q heads 0..15 cols h*128; k heads cols 2048+kv*128.
// qO: (B,16,T,128) bf16 (score scale folded in); kO: (B,4,T,128) bf16.
__global__ __launch_bounds__(64) void rope_rms_qk(const short* __restrict__ qkv,
                                                  const float* __restrict__ cosT,
                                                  const float* __restrict__ sinT,
                                                  short* __restrict__ qO,
                                                  short* __restrict__ kO) {
  const int T = 2048;
  int gid = blockIdx.x;
  int hh = gid % 20;
  int t = (gid / 20) % T;
  int b = gid / (20 * T);
  int lane = threadIdx.x;
  int col = hh < 16 ? hh * 128 : 2048 + (hh - 16) * 128;
  const short* src = qkv + (size_t)(b * T + t) * 3072 + col;
  float t1 = bits2f(src[lane]), t2 = bits2f(src[lane + 64]);
  float c = cosT[t * 64 + lane], s = sinT[t * 64 + lane];
  float o1 = t1 * c + t2 * s;
  float o2 = t2 * c - t1 * s;
  float ss = o1 * o1 + o2 * o2;
#pragma unroll
  for (int o = 1; o < 64; o <<= 1) ss += __shfl_xor(ss, o, 64);
  float r = rsqrtf(ss * (1.f / 128.f) + 1.1920929e-07f);
  short* dst;
  if (hh < 16) {
    r *= 0.08838834764831845f;  // 1/sqrt(128) folded into q
    dst = qO + ((size_t)(b * 16 + hh) * T + t) * 128;
  } else {
    dst = kO + ((size_t)(b * 4 + (hh - 16)) * T + t) * 128;
  }
  dst[lane] = f2bits(o1 * r);
  dst[lane + 64] = f2bits(o2 * r);
}

// ---------------- v = v + 2*sigmoid(x[:32]@wgate^T) * ve ----------------
__global__ __launch_bounds__(64) void v_gate(const short* __restrict__ qkv,
                                             const float* __restrict__ x,
                                             const float* __restrict__ ve,
                                             const float* __restrict__ wgate,
                                             short* __restrict__ vO) {
  const int T = 2048;
  int gid = blockIdx.x;
  int kv = gid & 3;
  int t = (gid >> 2) % T;
  int b = gid / (4 * T);
  int lane = threadIdx.x;
  size_t m = (size_t)b * T + t;
  float z = 0.f;
  if (lane < 32) z = x[m * 2048 + lane] * wgate[kv * 32 + lane];
#pragma unroll
  for (int o = 1; o < 64; o <<= 1) z += __shfl_xor(z, o, 64);
  float gate = 2.f / (1.f + __expf(-z));
  const short* vsrc = qkv + m * 3072 + 2560 + kv * 128;
  const float* vesrc = ve + m * 512 + kv * 128;
  short* dst = vO + ((size_t)(b * 4 + kv) * T + t) * 128;
  dst[lane] = f2bits(bits2f(vsrc[lane]) + gate * vesrc[lane]);
  dst[lane + 64] = f2bits(bits2f(vsrc[lane + 64]) + gate * vesrc[lane + 64]);
}

// ---------------- sliding-window flash attention ----------------
// Q: (B,16,T,128) (pre-scaled), K/V: (B,4,T,128), Y: (B,T,16,128) all bf16.
// Block = (b, h, 64 q-rows); 4 waves x 16 rows. 32-key chunks.
__global__ __launch_bounds__(256) void attn_sw(const short* __restrict__ Q,
                                               const short* __restrict__ K,
                                               const short* __restrict__ V,
                                               short* __restrict__ Y,
                                               const int* __restrict__ winp) {
  const int T = 2048, H = 16, D = 128;
  const int win = *winp;
  int qt = blockIdx.x & 31;
  int h = (blockIdx.x >> 5) & 15;
  int b = blockIdx.x >> 9;
  int q0 = qt * 64;
  int kvh = h >> 2;

  __shared__ __align__(16) short Ks[32 * 128];   // [key][d], XOR-swizzled
  __shared__ __align__(16) short Vs[128 * 56];   // [d][key] transposed, stride 56
  __shared__ __align__(16) short Ps[4][16 * 32]; // per-wave P tile

  int tid = threadIdx.x, wave = tid >> 6, lane = tid & 63;
  int rr = lane & 15, g = lane >> 4;
  int qw = q0 + wave * 16;

  const short* qbase = Q + ((size_t)(b * H + h) * T + qw) * D;
  short8_t qf[4];
#pragma unroll
  for (int ks = 0; ks < 4; ++ks)
    qf[ks] = *reinterpret_cast<const short8_t*>(qbase + rr * D + ks * 32 + g * 8);

  float mrow[4] = {-1e30f, -1e30f, -1e30f, -1e30f};
  float lrow[4] = {0.f, 0.f, 0.f, 0.f};
  f32x4 acc[8];
#pragma unroll
  for (int ct = 0; ct < 8; ++ct) acc[ct] = (f32x4){0.f, 0.f, 0.f, 0.f};

  const short* kbase = K + (size_t)(b * 4 + kvh) * T * D;
  const short* vbase = V + (size_t)(b * 4 + kvh) * T * D;
  int srow = tid >> 3, sds = (tid & 7) * 16;  // K staging: 32 rows x 128
  int vkk = tid & 31, vds = (tid >> 5) * 16;  // V staging: key fast-varying

  int lo = q0 - win + 1;
  if (lo < 0) lo = 0;
  lo &= ~31;

  for (int kc = lo; kc <= q0 + 63; kc += 32) {
    __syncthreads();
    {
      const short* ksrc = kbase + (size_t)(kc + srow) * D + sds;
      short8_t ka = *reinterpret_cast<const short8_t*>(ksrc);
      short8_t kb = *reinterpret_cast<const short8_t*>(ksrc + 8);
      int byte0 = srow * 256 + sds * 2;
      int sw = (srow & 7) << 4;
      *reinterpret_cast<short8_t*>((char*)Ks + (byte0 ^ sw)) = ka;
      *reinterpret_cast<short8_t*>((char*)Ks + ((byte0 + 16) ^ sw)) = kb;

      const short* vsrc = vbase + (size_t)(kc + vkk) * D + vds;
      short8_t va = *reinterpret_cast<const short8_t*>(vsrc);
      short8_t vb = *reinterpret_cast<const short8_t*>(vsrc + 8);
#pragma unroll
      for (int i = 0; i < 8; ++i) {
        Vs[(vds + i) * 56 + vkk] = va[i];
        Vs[(vds + 8 + i) * 56 + vkk] = vb[i];
      }
    }
    __syncthreads();

    // S = Q * K^T for 32 keys (two 16-col tiles)
    f32x4 s0 = (f32x4){0.f, 0.f, 0.f, 0.f}, s1 = (f32x4){0.f, 0.f, 0.f, 0.f};
#pragma unroll
    for (int ks = 0; ks < 4; ++ks) {
      int cb = (ks * 32 + g * 8) * 2;
      short8_t k0 = *reinterpret_cast<const short8_t*>((char*)Ks + ((rr * 256 + cb) ^ ((rr & 7) << 4)));
      short8_t k1 = *reinterpret_cast<const short8_t*>((char*)Ks + (((16 + rr) * 256 + cb) ^ ((rr & 7) << 4)));
      s0 = MFMA_BF16(qf[ks], k0, s0);
      s1 = MFMA_BF16(qf[ks], k1, s1);
    }

    // online softmax (rows live in 16-lane groups; 4 rows per lane as regs j)
    float p0[4], p1[4], corr[4];
#pragma unroll
    for (int j = 0; j < 4; ++j) {
      int row = qw + g * 4 + j;
      int key0 = kc + rr, key1 = kc + 16 + rr;
      bool ok0 = (key0 <= row) && (key0 > row - win);
      bool ok1 = (key1 <= row) && (key1 > row - win);
      float a0 = ok0 ? s0[j] : -1e30f;
      float a1 = ok1 ? s1[j] : -1e30f;
      float pm = fmaxf(a0, a1);
#pragma unroll
      for (int o = 1; o < 16; o <<= 1) pm = fmaxf(pm, __shfl_xor(pm, o, 64));
      float mn = fmaxf(mrow[j], pm);
      float e0 = ok0 ? __expf(s0[j] - mn) : 0.f;
      float e1 = ok1 ? __expf(s1[j] - mn) : 0.f;
      float rs = e0 + e1;
#pragma unroll
      for (int o = 1; o < 16; o <<= 1) rs += __shfl_xor(rs, o, 64);
      corr[j] = __expf(mrow[j] - mn);
      lrow[j] = lrow[j] * corr[j] + rs;
      mrow[j] = mn;
      p0[j] = e0;
      p1[j] = e1;
    }
#pragma unroll
    for (int ct = 0; ct < 8; ++ct) {
      f32x4 a = acc[ct];
      a[0] *= corr[0]; a[1] *= corr[1]; a[2] *= corr[2]; a[3] *= corr[3];
      acc[ct] = a;
    }

    // P tile -> LDS (bf16), then PV MFMAs
    char* pb = (char*)&Ps[wave][0];
#pragma unroll
    for (int j = 0; j < 4; ++j) {
      int prow = g * 4 + j;
      int pbyte = prow * 64 + rr * 2;
      int sw = (prow & 3) << 4;
      *reinterpret_cast<short*>(pb + (pbyte ^ sw)) = f2bits(p0[j]);
      *reinterpret_cast<short*>(pb + ((pbyte + 32) ^ sw)) = f2bits(p1[j]);
    }
    __syncthreads();
    short8_t pa = *reinterpret_cast<const short8_t*>(pb + ((rr * 64 + g * 16) ^ ((rr & 3) << 4)));
#pragma unroll
    for (int ct = 0; ct < 8; ++ct) {
      short8_t vf = *reinterpret_cast<const short8_t*>(&Vs[(ct * 16 + rr) * 56 + g * 8]);
      acc[ct] = MFMA_BF16(pa, vf, acc[ct]);
    }
  }

#pragma unroll
  for (int ct = 0; ct < 8; ++ct)
#pragma unroll
    for (int j = 0; j < 4; ++j) {
      int trow = qw + g * 4 + j;
      float o = acc[ct][j] / lrow[j];
      Y[((size_t)(b * T + trow) * H + h) * D + ct * 16 + rr] = f2bits(o);
    }
}

// ---------------- launcher ----------------
extern "C" void kernel_launch(void* const* d_in, const int* in_sizes, int n_in,
                              void* d_out, int out_size, void* d_ws, size_t ws_size,
                              hipStream_t stream) {
  const float* x = (const float*)d_in[0];
  const float* ve = (const float*)d_in[1];
  const float* cosT = (const float*)d_in[2];
  const float* sinT = (const float*)d_in[3];
  const float* wq = (const float*)d_in[4];
  const float* wk = (const float*)d_in[5];
  const float* wv = (const float*)d_in[6];
  const float* wo = (const float*)d_in[7];
  const float* wgate = (const float*)d_in[8];
  const int* winp = (const int*)d_in[9];
  float* out = (float*)d_out;
  char* ws = (char*)d_ws;

  const int B = 2, T = 2048;
  short* xb    = (short*)(ws);                 // 16 MB  (4096 x 2048 bf16)
  short* wqkvb = (short*)(ws + 16777216);      // 12 MB  (3072 x 2048 bf16)
  short* wob   = (short*)(ws + 29360128);      // 8 MB   (2048 x 2048 bf16)
  short* qkv   = (short*)(ws + 37748736);      // 24 MB  (4096 x 3072 bf16)
  short* qpost = (short*)(ws + 62914560);      // 16 MB  (B,16,T,128)
  short* kpost = (short*)(ws + 79691776);      // 4 MB   (B,4,T,128)
  short* vpost = (short*)(ws + 83886080);      // 4 MB   (B,4,T,128)
  short* ybuf  = (short*)(ws + 88080384);      // 16 MB  (B,T,16,128)

  auto cvt = [&](const float* src, short* dst, int n) {
    cvt_f32_bf16<<<dim3((n / 4 + 255) / 256), dim3(256), 0, stream>>>(src, dst, n);
  };
  cvt(x, xb, B * T * 2048);
  cvt(wq, wqkvb, 2048 * 2048);
  cvt(wk, wqkvb + 2048 * 2048, 512 * 2048);
  cvt(wv, wqkvb + 2560 * 2048, 512 * 2048);
  cvt(wo, wob, 2048 * 2048);

  gemm_bt<1><<<dim3(24, 32), 256, 0, stream>>>(xb, wqkvb, qkv, 4096, 3072, 2048);

  rope_rms_qk<<<dim3(B * T * 20), 64, 0, stream>>>(qkv, cosT, sinT, qpost, kpost);
  v_gate<<<dim3(B * T * 4), 64, 0, stream>>>(qkv, x, ve, wgate, vpost);

  attn_sw<<<dim3(B * 16 * (T / 64)), 256, 0, stream>>>(qpost, kpost, vpost, ybuf, winp);

  gemm_bt<0><<<dim3(16, 32), 256, 0, stream>>>(ybuf, wob, out, 4096, 2048, 2048);
}

// Round 2
// 215.875 us; speedup vs baseline: 1.1047x; 1.1047x over previous
//
#include <hip/hip_runtime.h>
#include <hip/hip_bf16.h>

typedef __attribute__((ext_vector_type(8))) short short8_t;
typedef __attribute__((ext_vector_type(4))) float f32x4;
typedef __attribute__((ext_vector_type(16))) float f32x16;
using bf16 = __hip_bfloat16;

#define MFMA_BF16(A, B, C) __builtin_amdgcn_mfma_f32_16x16x32_bf16((A), (B), (C), 0, 0, 0)
#define MFMA32_BF16(A, B, C) __builtin_amdgcn_mfma_f32_32x32x16_bf16((A), (B), (C), 0, 0, 0)

#define GLD_LDS16(g, l)                                                        \
  __builtin_amdgcn_global_load_lds(                                           \
      (const __attribute__((address_space(1))) unsigned int*)(const void*)(g),\
      (__attribute__((address_space(3))) unsigned int*)(void*)(l), 16, 0, 0)

__device__ __forceinline__ float bits2f(short s) {
  union { unsigned int u; float f; } c;
  c.u = ((unsigned int)(unsigned short)s) << 16;
  return c.f;
}
__device__ __forceinline__ short f2bits(float f) {
  bf16 h = __float2bfloat16(f);
  return *reinterpret_cast<short*>(&h);
}
__device__ __forceinline__ unsigned pack2(float lo, float hi) {
  return ((unsigned)(unsigned short)f2bits(lo)) |
         (((unsigned)(unsigned short)f2bits(hi)) << 16);
}
__device__ __forceinline__ float exp2_(float x) {
#if __has_builtin(__builtin_amdgcn_exp2f)
  return __builtin_amdgcn_exp2f(x);
#else
  return exp2f(x);
#endif
}

// ---------------- fp32 -> bf16 convert (vectorized) ----------------
__global__ __launch_bounds__(256) void cvt_f32_bf16(const float* __restrict__ in,
                                                    short* __restrict__ out, int n) {
  int i = (blockIdx.x * 256 + threadIdx.x) * 4;
  if (i >= n) return;
  float4 v = *reinterpret_cast<const float4*>(in + i);
  short4 o;
  o.x = f2bits(v.x); o.y = f2bits(v.y); o.z = f2bits(v.z); o.w = f2bits(v.w);
  *reinterpret_cast<short4*>(out + i) = o;
}

// ---------------- bf16 B^T GEMM: C[m][n] = sum_k A[m][k] * Bt[n][k] ----------------
template <int STORE_BF16>
__global__ __launch_bounds__(256) void gemm_bt(const short* __restrict__ A,
                                               const short* __restrict__ Bt,
                                               void* __restrict__ C, int M, int N, int K) {
  __shared__ __align__(16) short As[128 * 32];
  __shared__ __align__(16) short Bs[128 * 32];
  const int m0 = blockIdx.y * 128, n0 = blockIdx.x * 128;
  const int tid = threadIdx.x, wave = tid >> 6, lane = tid & 63;
  const int wr = wave >> 1, wc = wave & 1;
  const int rr = lane & 15, g = lane >> 4;

  f32x4 acc[4][4];
#pragma unroll
  for (int mi = 0; mi < 4; ++mi)
#pragma unroll
    for (int ni = 0; ni < 4; ++ni) acc[mi][ni] = (f32x4){0.f, 0.f, 0.f, 0.f};

  const int srow = wave * 32 + (lane >> 2);
  const int scol = (lane & 3) * 8;
  const short* Abase = A + (size_t)(m0 + srow) * K + scol;
  const short* Bbase = Bt + (size_t)(n0 + srow) * K + scol;

  for (int k0 = 0; k0 < K; k0 += 32) {
    if (k0) __syncthreads();
    GLD_LDS16(Abase + k0, &As[wave * 1024]);
    GLD_LDS16(Abase + 16 * (size_t)K + k0, &As[wave * 1024 + 512]);
    GLD_LDS16(Bbase + k0, &Bs[wave * 1024]);
    GLD_LDS16(Bbase + 16 * (size_t)K + k0, &Bs[wave * 1024 + 512]);
    __syncthreads();

    short8_t af[4], bfv[4];
#pragma unroll
    for (int mi = 0; mi < 4; ++mi)
      af[mi] = *reinterpret_cast<const short8_t*>(&As[(wr * 64 + mi * 16 + rr) * 32 + g * 8]);
#pragma unroll
    for (int ni = 0; ni < 4; ++ni)
      bfv[ni] = *reinterpret_cast<const short8_t*>(&Bs[(wc * 64 + ni * 16 + rr) * 32 + g * 8]);
#pragma unroll
    for (int mi = 0; mi < 4; ++mi)
#pragma unroll
      for (int ni = 0; ni < 4; ++ni)
        acc[mi][ni] = MFMA_BF16(af[mi], bfv[ni], acc[mi][ni]);
  }

#pragma unroll
  for (int mi = 0; mi < 4; ++mi)
#pragma unroll
    for (int ni = 0; ni < 4; ++ni) {
      const int row = m0 + wr * 64 + mi * 16 + g * 4;
      const int col = n0 + wc * 64 + ni * 16 + rr;
#pragma unroll
      for (int j = 0; j < 4; ++j) {
        float v = acc[mi][ni][j];
        if (STORE_BF16)
          reinterpret_cast<short*>(C)[(size_t)(row + j) * N + col] = f2bits(v);
        else
          reinterpret_cast<float*>(C)[(size_t)(row + j) * N + col] = v;
      }
    }
}

// ---------------- RoPE + RMS for q and k ----------------
// q scale: 1/sqrt(128) * log2(e) folded in (attention uses exp2).
__global__ __launch_bounds__(64) void rope_rms_qk(const short* __restrict__ qkv,
                                                  const float* __restrict__ cosT,
                                                  const float* __restrict__ sinT,
                                                  short* __restrict__ qO,
                                                  short* __restrict__ kO) {
  const int T = 2048;
  int gid = blockIdx.x;
  int hh = gid % 20;
  int t = (gid / 20) % T;
  int b = gid / (20 * T);
  int lane = threadIdx.x;
  int col = hh < 16 ? hh * 128 : 2048 + (hh - 16) * 128;
  const short* src = qkv + (size_t)(b * T + t) * 3072 + col;
  float t1 = bits2f(src[lane]), t2 = bits2f(src[lane + 64]);
  float c = cosT[t * 64 + lane], s = sinT[t * 64 + lane];
  float o1 = t1 * c + t2 * s;
  float o2 = t2 * c - t1 * s;
  float ss = o1 * o1 + o2 * o2;
#pragma unroll
  for (int o = 1; o < 64; o <<= 1) ss += __shfl_xor(ss, o, 64);
  float r = rsqrtf(ss * (1.f / 128.f) + 1.1920929e-07f);
  short* dst;
  if (hh < 16) {
    r *= 0.08838834764831845f * 1.4426950408889634f;  // 1/sqrt(128) * log2e
    dst = qO + ((size_t)(b * 16 + hh) * T + t) * 128;
  } else {
    dst = kO + ((size_t)(b * 4 + (hh - 16)) * T + t) * 128;
  }
  dst[lane] = f2bits(o1 * r);
  dst[lane + 64] = f2bits(o2 * r);
}

// ---------------- v = v + 2*sigmoid(x[:32]@wgate^T) * ve ----------------
__global__ __launch_bounds__(64) void v_gate(const short* __restrict__ qkv,
                                             const float* __restrict__ x,
                                             const float* __restrict__ ve,
                                             const float* __restrict__ wgate,
                                             short* __restrict__ vO) {
  const int T = 2048;
  int gid = blockIdx.x;
  int kv = gid & 3;
  int t = (gid >> 2) % T;
  int b = gid / (4 * T);
  int lane = threadIdx.x;
  size_t m = (size_t)b * T + t;
  float z = 0.f;
  if (lane < 32) z = x[m * 2048 + lane] * wgate[kv * 32 + lane];
#pragma unroll
  for (int o = 1; o < 64; o <<= 1) z += __shfl_xor(z, o, 64);
  float gate = 2.f / (1.f + __expf(-z));
  const short* vsrc = qkv + m * 3072 + 2560 + kv * 128;
  const float* vesrc = ve + m * 512 + kv * 128;
  short* dst = vO + ((size_t)(b * 4 + kv) * T + t) * 128;
  dst[lane] = f2bits(bits2f(vsrc[lane]) + gate * vesrc[lane]);
  dst[lane + 64] = f2bits(bits2f(vsrc[lane + 64]) + gate * vesrc[lane + 64]);
}

// ---------------- sliding-window flash attention, swapped-QK 32x32 ----------------
// Block = (b,kvh,h,128 q-rows); 4 waves x 32 q-rows; 64-key chunks.
// S^T = K·Q^T via mfma_32x32x16 (lane's col = its q-row -> lane-local softmax).
// O^T = V^T·P^T (corr rescale is one scalar per lane).
__global__ __launch_bounds__(256) void attn_sw2(const short* __restrict__ Q,
                                                const short* __restrict__ K,
                                                const short* __restrict__ V,
                                                short* __restrict__ Y,
                                                const int* __restrict__ winp) {
  const int T = 2048, H = 16;
  const int win = *winp;
  int combo = blockIdx.x & 7;          // (b,kvh) -> XCD pin
  int j = blockIdx.x >> 3;
  int b = combo >> 2, kvh = combo & 3;
  int h = kvh * 4 + (j & 3);
  int q0 = (j >> 2) * 128;

  __shared__ __align__(16) short Ks[64 * 128];  // [key][d], granule-XOR swizzled
  __shared__ __align__(16) short Vs[128 * 64];  // [d][key], granule-XOR swizzled

  int tid = threadIdx.x, w = tid >> 6, lane = tid & 63;
  int ql = lane & 31, hi = lane >> 5;
  int qrow = q0 + w * 32 + ql;

  // Q fragments: B-operand, lane holds Q[qrow][ks*16 + hi*8 .. +7]
  const short* qbase = Q + ((size_t)(b * H + h) * T + qrow) * 128;
  short8_t qf[8];
#pragma unroll
  for (int ks = 0; ks < 8; ++ks)
    qf[ks] = *reinterpret_cast<const short8_t*>(qbase + ks * 16 + hi * 8);

  const short* kbase = K + (size_t)(b * 4 + kvh) * T * 128;
  const short* vbase = V + (size_t)(b * 4 + kvh) * T * 128;

  f32x16 acc[4];
#pragma unroll
  for (int dt = 0; dt < 4; ++dt)
#pragma unroll
    for (int r = 0; r < 16; ++r) acc[dt][r] = 0.f;
  float mreg = -1e30f, lsum = 0.f;

  int vkey = tid >> 2;  // V staging: 0..63
  int vdc = tid & 3;    // d-block 0..3

  int lo = q0 - win + 1;
  if (lo < 0) lo = 0;
  lo &= ~63;
  int qmin = q0 + w * 32, qmax = qmin + 31;

  for (int kc = lo; kc < q0 + 128; kc += 64) {
    __syncthreads();
    // ---- K staging via global_load_lds, pre-swizzled source (m173 pattern) ----
#pragma unroll
    for (int r = 0; r < 4; ++r) {
      int slot = (r * 4 + w) * 64 + lane;      // 16B granule index
      int krow = slot >> 4;                    // 16 granules per 256B row
      int c16 = (slot & 15) ^ (krow & 7);
      GLD_LDS16(kbase + (size_t)(kc + krow) * 128 + c16 * 8,
                (char*)Ks + (r * 4 + w) * 1024);
    }
    // ---- V staging: coalesced row read, transposed swizzled scalar writes ----
    {
      const short* vsrc = vbase + (size_t)(kc + vkey) * 128 + vdc * 32;
      short8_t vv[4];
#pragma unroll
      for (int q2 = 0; q2 < 4; ++q2)
        vv[q2] = *reinterpret_cast<const short8_t*>(vsrc + q2 * 8);
#pragma unroll
      for (int i = 0; i < 32; ++i) {
        int d = vdc * 32 + i;
        int byte = d * 128 + vkey * 2;
        byte ^= ((i & 7) ^ vdc) << 4;  // (d&7)^((d>>5)&3) granule swizzle
        *reinterpret_cast<short*>((char*)Vs + byte) = vv[i >> 3][i & 7];
      }
    }
    __syncthreads();

    bool active = (kc <= qmax) && (kc + 63 >= qmin - win + 1);
    if (active) {
      // ---- S^T = K·Q^T ----
      f32x16 sA[2];
#pragma unroll
      for (int r = 0; r < 16; ++r) { sA[0][r] = 0.f; sA[1][r] = 0.f; }
#pragma unroll
      for (int kt = 0; kt < 2; ++kt) {
        int kr = kt * 32 + ql;
#pragma unroll
        for (int ks = 0; ks < 8; ++ks) {
          int byte = kr * 256 + (((ks * 2 + hi) ^ (kr & 7)) << 4);
          short8_t kf = *reinterpret_cast<const short8_t*>((char*)Ks + byte);
          sA[kt] = MFMA32_BF16(kf, qf[ks], sA[kt]);
        }
      }
      // ---- mask + lane-local online softmax (scores pre-scaled to log2 domain) ----
      float pmax = -1e30f;
#pragma unroll
      for (int kt = 0; kt < 2; ++kt)
#pragma unroll
        for (int r = 0; r < 16; ++r) {
          int key = kc + kt * 32 + (r & 3) + 8 * (r >> 2) + 4 * hi;
          float sv = sA[kt][r];
          sv = ((unsigned)(qrow - key) < (unsigned)win) ? sv : -1e30f;
          sA[kt][r] = sv;
          pmax = fmaxf(pmax, sv);
        }
      pmax = fmaxf(pmax, __shfl_xor(pmax, 32, 64));
      float mn = fmaxf(mreg, pmax);
      float corr = exp2_(mreg - mn);
      mreg = mn;
      float rs = 0.f;
#pragma unroll
      for (int kt = 0; kt < 2; ++kt)
#pragma unroll
        for (int r = 0; r < 16; ++r) {
          float p = exp2_(sA[kt][r] - mn);
          sA[kt][r] = p;
          rs += p;
        }
      rs += __shfl_xor(rs, 32, 64);
      lsum = lsum * corr + rs;
#pragma unroll
      for (int dt = 0; dt < 4; ++dt)
#pragma unroll
        for (int r = 0; r < 16; ++r) acc[dt][r] *= corr;

      // ---- P^T exchange (pack + half-wave shfl) + PV: O^T += V^T · P^T ----
#pragma unroll
      for (int kt = 0; kt < 2; ++kt)
#pragma unroll
        for (int s = 0; s < 2; ++s) {
          unsigned a = pack2(sA[kt][8 * s + 0], sA[kt][8 * s + 1]);
          unsigned bb = pack2(sA[kt][8 * s + 2], sA[kt][8 * s + 3]);
          unsigned c = pack2(sA[kt][8 * s + 4], sA[kt][8 * s + 5]);
          unsigned d = pack2(sA[kt][8 * s + 6], sA[kt][8 * s + 7]);
          unsigned sa = __shfl_xor(a, 32, 64);
          unsigned sb = __shfl_xor(bb, 32, 64);
          unsigned sc = __shfl_xor(c, 32, 64);
          unsigned sd = __shfl_xor(d, 32, 64);
          union { unsigned u[4]; short8_t s8; } pu;
          pu.u[0] = hi ? sc : a;   // {a_lo, c_lo}
          pu.u[1] = hi ? sd : bb;  // {b_lo, d_lo}
          pu.u[2] = hi ? c : sa;   // {a_hi, c_hi}
          pu.u[3] = hi ? d : sb;   // {b_hi, d_hi}
          int kb = kt * 64 + s * 32 + hi * 16;  // key byte base in Vs row
#pragma unroll
          for (int dt = 0; dt < 4; ++dt) {
            int drow = dt * 32 + ql;
            int byte = drow * 128 + kb;
            byte ^= ((drow & 7) ^ dt) << 4;
            short8_t vf = *reinterpret_cast<const short8_t*>((char*)Vs + byte);
            acc[dt] = MFMA32_BF16(vf, pu.s8, acc[dt]);
          }
        }
    }
  }

  float rinv = 1.f / lsum;
  short* ybase = Y + ((size_t)(b * T + qrow) * H + h) * 128;
#pragma unroll
  for (int dt = 0; dt < 4; ++dt)
#pragma unroll
    for (int g2 = 0; g2 < 4; ++g2) {
      short4 o;
      o.x = f2bits(acc[dt][g2 * 4 + 0] * rinv);
      o.y = f2bits(acc[dt][g2 * 4 + 1] * rinv);
      o.z = f2bits(acc[dt][g2 * 4 + 2] * rinv);
      o.w = f2bits(acc[dt][g2 * 4 + 3] * rinv);
      *reinterpret_cast<short4*>(ybase + dt * 32 + 8 * g2 + 4 * hi) = o;
    }
}

// ---------------- launcher ----------------
extern "C" void kernel_launch(void* const* d_in, const int* in_sizes, int n_in,
                              void* d_out, int out_size, void* d_ws, size_t ws_size,
                              hipStream_t stream) {
  const float* x = (const float*)d_in[0];
  const float* ve = (const float*)d_in[1];
  const float* cosT = (const float*)d_in[2];
  const float* sinT = (const float*)d_in[3];
  const float* wq = (const float*)d_in[4];
  const float* wk = (const float*)d_in[5];
  const float* wv = (const float*)d_in[6];
  const float* wo = (const float*)d_in[7];
  const float* wgate = (const float*)d_in[8];
  const int* winp = (const int*)d_in[9];
  float* out = (float*)d_out;
  char* ws = (char*)d_ws;

  const int B = 2, T = 2048;
  short* xb    = (short*)(ws);
  short* wqkvb = (short*)(ws + 16777216);
  short* wob   = (short*)(ws + 29360128);
  short* qkv   = (short*)(ws + 37748736);
  short* qpost = (short*)(ws + 62914560);
  short* kpost = (short*)(ws + 79691776);
  short* vpost = (short*)(ws + 83886080);
  short* ybuf  = (short*)(ws + 88080384);

  auto cvt = [&](const float* src, short* dst, int n) {
    cvt_f32_bf16<<<dim3((n / 4 + 255) / 256), dim3(256), 0, stream>>>(src, dst, n);
  };
  cvt(x, xb, B * T * 2048);
  cvt(wq, wqkvb, 2048 * 2048);
  cvt(wk, wqkvb + 2048 * 2048, 512 * 2048);
  cvt(wv, wqkvb + 2560 * 2048, 512 * 2048);
  cvt(wo, wob, 2048 * 2048);

  gemm_bt<1><<<dim3(24, 32), 256, 0, stream>>>(xb, wqkvb, qkv, 4096, 3072, 2048);

  rope_rms_qk<<<dim3(B * T * 20), 64, 0, stream>>>(qkv, cosT, sinT, qpost, kpost);
  v_gate<<<dim3(B * T * 4), 64, 0, stream>>>(qkv, x, ve, wgate, vpost);

  attn_sw2<<<dim3(512), 256, 0, stream>>>(qpost, kpost, vpost, ybuf, winp);

  gemm_bt<0><<<dim3(16, 32), 256, 0, stream>>>(ybuf, wob, out, 4096, 2048, 2048);
}

// Round 3
// 212.670 us; speedup vs baseline: 1.1214x; 1.0151x over previous
//
#include <hip/hip_runtime.h>
#include <hip/hip_bf16.h>

typedef __attribute__((ext_vector_type(8))) short short8_t;
typedef __attribute__((ext_vector_type(4))) float f32x4;
typedef __attribute__((ext_vector_type(16))) float f32x16;
using bf16 = __hip_bfloat16;

#define MFMA_BF16(A, B, C) __builtin_amdgcn_mfma_f32_16x16x32_bf16((A), (B), (C), 0, 0, 0)
#define MFMA32_BF16(A, B, C) __builtin_amdgcn_mfma_f32_32x32x16_bf16((A), (B), (C), 0, 0, 0)

#define GLD_LDS16(g, l)                                                        \
  __builtin_amdgcn_global_load_lds(                                           \
      (const __attribute__((address_space(1))) unsigned int*)(const void*)(g),\
      (__attribute__((address_space(3))) unsigned int*)(void*)(l), 16, 0, 0)

__device__ __forceinline__ float bits2f(short s) {
  union { unsigned int u; float f; } c;
  c.u = ((unsigned int)(unsigned short)s) << 16;
  return c.f;
}
__device__ __forceinline__ short f2bits(float f) {
  bf16 h = __float2bfloat16(f);
  return *reinterpret_cast<short*>(&h);
}
__device__ __forceinline__ unsigned pack2(float lo, float hi) {
  return ((unsigned)(unsigned short)f2bits(lo)) |
         (((unsigned)(unsigned short)f2bits(hi)) << 16);
}
__device__ __forceinline__ float exp2_(float x) {
#if __has_builtin(__builtin_amdgcn_exp2f)
  return __builtin_amdgcn_exp2f(x);
#else
  return exp2f(x);
#endif
}

// ---------------- fp32 -> bf16 convert (vectorized) ----------------
__global__ __launch_bounds__(256) void cvt_f32_bf16(const float* __restrict__ in,
                                                    short* __restrict__ out, int n) {
  int i = (blockIdx.x * 256 + threadIdx.x) * 4;
  if (i >= n) return;
  float4 v = *reinterpret_cast<const float4*>(in + i);
  short4 o;
  o.x = f2bits(v.x); o.y = f2bits(v.y); o.z = f2bits(v.z); o.w = f2bits(v.w);
  *reinterpret_cast<short4*>(out + i) = o;
}

// ---------------- bf16 B^T GEMM v2: C[m][n] = sum_k A[m][k] * Bt[n][k] ----------------
// BM=256 BN=128 BK=32, 8 waves (2x4), double-buffered LDS (48 KB), prefetch
// issued at iter top (aged ~1 phase at the barrier drain), XOR-swizzled LDS
// (conflict-free ds_read_b128), XCD-swizzled 1D grid. nwg must be %8==0.
template <int STORE_BF16>
__global__ __launch_bounds__(512, 4) void gemm_bt2(const short* __restrict__ A,
                                                   const short* __restrict__ Bt,
                                                   void* __restrict__ C,
                                                   int M, int N, int K, int NBN) {
  __shared__ __align__(16) short lds[2 * 12288];  // per buf: A 16KB + B 8KB
  const int nwg = gridDim.x;
  const int cpx = nwg >> 3;
  const int wg = ((int)blockIdx.x & 7) * cpx + ((int)blockIdx.x >> 3);
  const int m0 = (wg / NBN) * 256, n0 = (wg % NBN) * 128;

  const int tid = threadIdx.x, w = tid >> 6, lane = tid & 63;
  const int wr = w >> 2, wc = w & 3;
  const int rr = lane & 15, g = lane >> 4;

  // staging source decode: dest granule byte d (linear) -> logical (row, c)
  // of swizzle phys = ((row<<6)|(c<<4)|sub) ^ ((row&7)<<4)
  const int d = tid * 16;
  const int sr0 = ((d >> 6) & 1) ^ ((d >> 8) & 1);
  const int srow = ((d >> 7) << 1) | sr0;
  const int sc = ((d >> 4) & 3) ^ (srow & 3);
  const short* Asrc = A + (size_t)(m0 + srow) * K + sc * 8;
  const short* Bsrc = Bt + (size_t)(n0 + srow) * K + sc * 8;

  // swizzled ds_read byte offsets (row&7 == rr&7 for all frags)
  const int arow = wr * 128 + rr;
  const int abyte0 = ((arow << 6) | (g << 4)) ^ ((rr & 7) << 4);
  const int brow0 = wc * 32 + rr;
  const int bbyte0 = ((brow0 << 6) | (g << 4)) ^ ((rr & 7) << 4);

  f32x4 acc[8][2];
#pragma unroll
  for (int mi = 0; mi < 8; ++mi) {
    acc[mi][0] = (f32x4){0.f, 0.f, 0.f, 0.f};
    acc[mi][1] = (f32x4){0.f, 0.f, 0.f, 0.f};
  }

  const int ldst = w * 512;  // wave-uniform dest offset (shorts)
  const int nt = K >> 5;

  // prologue: tile 0 -> buf 0
  GLD_LDS16(Asrc, lds + ldst);
  GLD_LDS16(Asrc + (size_t)128 * K, lds + 4096 + ldst);
  GLD_LDS16(Bsrc, lds + 8192 + ldst);
  __syncthreads();

  int cur = 0;
  for (int t = 0; t < nt; ++t) {
    if (t + 1 < nt) {  // prefetch tile t+1 into the other buffer
      const short* a2 = Asrc + (t + 1) * 32;
      const short* b2 = Bsrc + (t + 1) * 32;
      short* dst = lds + (cur ^ 1) * 12288;
      GLD_LDS16(a2, dst + ldst);
      GLD_LDS16(a2 + (size_t)128 * K, dst + 4096 + ldst);
      GLD_LDS16(b2, dst + 8192 + ldst);
    }
    const char* As_ = (const char*)(lds + cur * 12288);
    const char* Bs_ = As_ + 16384;
    short8_t b0 = *(const short8_t*)(Bs_ + bbyte0);
    short8_t b1 = *(const short8_t*)(Bs_ + bbyte0 + 1024);
    __builtin_amdgcn_s_setprio(1);
#pragma unroll
    for (int mi = 0; mi < 8; ++mi) {
      short8_t a = *(const short8_t*)(As_ + abyte0 + mi * 1024);
      acc[mi][0] = MFMA_BF16(a, b0, acc[mi][0]);
      acc[mi][1] = MFMA_BF16(a, b1, acc[mi][1]);
    }
    __builtin_amdgcn_s_setprio(0);
    __syncthreads();  // drains vmcnt (aged prefetch) + lgkm, then barrier
    cur ^= 1;
  }

#pragma unroll
  for (int mi = 0; mi < 8; ++mi)
#pragma unroll
    for (int ni = 0; ni < 2; ++ni) {
      const int row = m0 + wr * 128 + mi * 16 + g * 4;
      const int col = n0 + wc * 32 + ni * 16 + rr;
#pragma unroll
      for (int j = 0; j < 4; ++j) {
        float v = acc[mi][ni][j];
        if (STORE_BF16)
          reinterpret_cast<short*>(C)[(size_t)(row + j) * N + col] = f2bits(v);
        else
          reinterpret_cast<float*>(C)[(size_t)(row + j) * N + col] = v;
      }
    }
}

// ---------------- RoPE + RMS for q and k ----------------
// q scale: 1/sqrt(128) * log2(e) folded in (attention uses exp2).
__global__ __launch_bounds__(64) void rope_rms_qk(const short* __restrict__ qkv,
                                                  const float* __restrict__ cosT,
                                                  const float* __restrict__ sinT,
                                                  short* __restrict__ qO,
                                                  short* __restrict__ kO) {
  const int T = 2048;
  int gid = blockIdx.x;
  int hh = gid % 20;
  int t = (gid / 20) % T;
  int b = gid / (20 * T);
  int lane = threadIdx.x;
  int col = hh < 16 ? hh * 128 : 2048 + (hh - 16) * 128;
  const short* src = qkv + (size_t)(b * T + t) * 3072 + col;
  float t1 = bits2f(src[lane]), t2 = bits2f(src[lane + 64]);
  float c = cosT[t * 64 + lane], s = sinT[t * 64 + lane];
  float o1 = t1 * c + t2 * s;
  float o2 = t2 * c - t1 * s;
  float ss = o1 * o1 + o2 * o2;
#pragma unroll
  for (int o = 1; o < 64; o <<= 1) ss += __shfl_xor(ss, o, 64);
  float r = rsqrtf(ss * (1.f / 128.f) + 1.1920929e-07f);
  short* dst;
  if (hh < 16) {
    r *= 0.08838834764831845f * 1.4426950408889634f;  // 1/sqrt(128) * log2e
    dst = qO + ((size_t)(b * 16 + hh) * T + t) * 128;
  } else {
    dst = kO + ((size_t)(b * 4 + (hh - 16)) * T + t) * 128;
  }
  dst[lane] = f2bits(o1 * r);
  dst[lane + 64] = f2bits(o2 * r);
}

// ---------------- v = v + 2*sigmoid(x[:32]@wgate^T) * ve ----------------
__global__ __launch_bounds__(64) void v_gate(const short* __restrict__ qkv,
                                             const float* __restrict__ x,
                                             const float* __restrict__ ve,
                                             const float* __restrict__ wgate,
                                             short* __restrict__ vO) {
  const int T = 2048;
  int gid = blockIdx.x;
  int kv = gid & 3;
  int t = (gid >> 2) % T;
  int b = gid / (4 * T);
  int lane = threadIdx.x;
  size_t m = (size_t)b * T + t;
  float z = 0.f;
  if (lane < 32) z = x[m * 2048 + lane] * wgate[kv * 32 + lane];
#pragma unroll
  for (int o = 1; o < 64; o <<= 1) z += __shfl_xor(z, o, 64);
  float gate = 2.f / (1.f + __expf(-z));
  const short* vsrc = qkv + m * 3072 + 2560 + kv * 128;
  const float* vesrc = ve + m * 512 + kv * 128;
  short* dst = vO + ((size_t)(b * 4 + kv) * T + t) * 128;
  dst[lane] = f2bits(bits2f(vsrc[lane]) + gate * vesrc[lane]);
  dst[lane + 64] = f2bits(bits2f(vsrc[lane + 64]) + gate * vesrc[lane + 64]);
}

// ---------------- sliding-window flash attention, swapped-QK 32x32 ----------------
__global__ __launch_bounds__(256) void attn_sw2(const short* __restrict__ Q,
                                                const short* __restrict__ K,
                                                const short* __restrict__ V,
                                                short* __restrict__ Y,
                                                const int* __restrict__ winp) {
  const int T = 2048, H = 16;
  const int win = *winp;
  int combo = blockIdx.x & 7;          // (b,kvh) -> XCD pin
  int j = blockIdx.x >> 3;
  int b = combo >> 2, kvh = combo & 3;
  int h = kvh * 4 + (j & 3);
  int q0 = (j >> 2) * 128;

  __shared__ __align__(16) short Ks[64 * 128];  // [key][d], granule-XOR swizzled
  __shared__ __align__(16) short Vs[128 * 64];  // [d][key], granule-XOR swizzled

  int tid = threadIdx.x, w = tid >> 6, lane = tid & 63;
  int ql = lane & 31, hi = lane >> 5;
  int qrow = q0 + w * 32 + ql;

  const short* qbase = Q + ((size_t)(b * H + h) * T + qrow) * 128;
  short8_t qf[8];
#pragma unroll
  for (int ks = 0; ks < 8; ++ks)
    qf[ks] = *reinterpret_cast<const short8_t*>(qbase + ks * 16 + hi * 8);

  const short* kbase = K + (size_t)(b * 4 + kvh) * T * 128;
  const short* vbase = V + (size_t)(b * 4 + kvh) * T * 128;

  f32x16 acc[4];
#pragma unroll
  for (int dt = 0; dt < 4; ++dt)
#pragma unroll
    for (int r = 0; r < 16; ++r) acc[dt][r] = 0.f;
  float mreg = -1e30f, lsum = 0.f;

  int vkey = tid >> 2;
  int vdc = tid & 3;

  int lo = q0 - win + 1;
  if (lo < 0) lo = 0;
  lo &= ~63;
  int qmin = q0 + w * 32, qmax = qmin + 31;

  for (int kc = lo; kc < q0 + 128; kc += 64) {
    __syncthreads();
#pragma unroll
    for (int r = 0; r < 4; ++r) {
      int slot = (r * 4 + w) * 64 + lane;
      int krow = slot >> 4;
      int c16 = (slot & 15) ^ (krow & 7);
      GLD_LDS16(kbase + (size_t)(kc + krow) * 128 + c16 * 8,
                (char*)Ks + (r * 4 + w) * 1024);
    }
    {
      const short* vsrc = vbase + (size_t)(kc + vkey) * 128 + vdc * 32;
      short8_t vv[4];
#pragma unroll
      for (int q2 = 0; q2 < 4; ++q2)
        vv[q2] = *reinterpret_cast<const short8_t*>(vsrc + q2 * 8);
#pragma unroll
      for (int i = 0; i < 32; ++i) {
        int dd = vdc * 32 + i;
        int byte = dd * 128 + vkey * 2;
        byte ^= ((i & 7) ^ vdc) << 4;
        *reinterpret_cast<short*>((char*)Vs + byte) = vv[i >> 3][i & 7];
      }
    }
    __syncthreads();

    bool active = (kc <= qmax) && (kc + 63 >= qmin - win + 1);
    if (active) {
      f32x16 sA[2];
#pragma unroll
      for (int r = 0; r < 16; ++r) { sA[0][r] = 0.f; sA[1][r] = 0.f; }
#pragma unroll
      for (int kt = 0; kt < 2; ++kt) {
        int kr = kt * 32 + ql;
#pragma unroll
        for (int ks = 0; ks < 8; ++ks) {
          int byte = kr * 256 + (((ks * 2 + hi) ^ (kr & 7)) << 4);
          short8_t kf = *reinterpret_cast<const short8_t*>((char*)Ks + byte);
          sA[kt] = MFMA32_BF16(kf, qf[ks], sA[kt]);
        }
      }
      float pmax = -1e30f;
#pragma unroll
      for (int kt = 0; kt < 2; ++kt)
#pragma unroll
        for (int r = 0; r < 16; ++r) {
          int key = kc + kt * 32 + (r & 3) + 8 * (r >> 2) + 4 * hi;
          float sv = sA[kt][r];
          sv = ((unsigned)(qrow - key) < (unsigned)win) ? sv : -1e30f;
          sA[kt][r] = sv;
          pmax = fmaxf(pmax, sv);
        }
      pmax = fmaxf(pmax, __shfl_xor(pmax, 32, 64));
      float mn = fmaxf(mreg, pmax);
      float corr = exp2_(mreg - mn);
      mreg = mn;
      float rs = 0.f;
#pragma unroll
      for (int kt = 0; kt < 2; ++kt)
#pragma unroll
        for (int r = 0; r < 16; ++r) {
          float p = exp2_(sA[kt][r] - mn);
          sA[kt][r] = p;
          rs += p;
        }
      rs += __shfl_xor(rs, 32, 64);
      lsum = lsum * corr + rs;
#pragma unroll
      for (int dt = 0; dt < 4; ++dt)
#pragma unroll
        for (int r = 0; r < 16; ++r) acc[dt][r] *= corr;

#pragma unroll
      for (int kt = 0; kt < 2; ++kt)
#pragma unroll
        for (int s = 0; s < 2; ++s) {
          unsigned a = pack2(sA[kt][8 * s + 0], sA[kt][8 * s + 1]);
          unsigned bb = pack2(sA[kt][8 * s + 2], sA[kt][8 * s + 3]);
          unsigned c = pack2(sA[kt][8 * s + 4], sA[kt][8 * s + 5]);
          unsigned dd = pack2(sA[kt][8 * s + 6], sA[kt][8 * s + 7]);
          unsigned sa = __shfl_xor(a, 32, 64);
          unsigned sb = __shfl_xor(bb, 32, 64);
          unsigned sc2 = __shfl_xor(c, 32, 64);
          unsigned sd = __shfl_xor(dd, 32, 64);
          union { unsigned u[4]; short8_t s8; } pu;
          pu.u[0] = hi ? sc2 : a;
          pu.u[1] = hi ? sd : bb;
          pu.u[2] = hi ? c : sa;
          pu.u[3] = hi ? dd : sb;
          int kb = kt * 64 + s * 32 + hi * 16;
#pragma unroll
          for (int dt = 0; dt < 4; ++dt) {
            int drow = dt * 32 + ql;
            int byte = drow * 128 + kb;
            byte ^= ((drow & 7) ^ dt) << 4;
            short8_t vf = *reinterpret_cast<const short8_t*>((char*)Vs + byte);
            acc[dt] = MFMA32_BF16(vf, pu.s8, acc[dt]);
          }
        }
    }
  }

  float rinv = 1.f / lsum;
  short* ybase = Y + ((size_t)(b * T + qrow) * H + h) * 128;
#pragma unroll
  for (int dt = 0; dt < 4; ++dt)
#pragma unroll
    for (int g2 = 0; g2 < 4; ++g2) {
      short4 o;
      o.x = f2bits(acc[dt][g2 * 4 + 0] * rinv);
      o.y = f2bits(acc[dt][g2 * 4 + 1] * rinv);
      o.z = f2bits(acc[dt][g2 * 4 + 2] * rinv);
      o.w = f2bits(acc[dt][g2 * 4 + 3] * rinv);
      *reinterpret_cast<short4*>(ybase + dt * 32 + 8 * g2 + 4 * hi) = o;
    }
}

// ---------------- launcher ----------------
extern "C" void kernel_launch(void* const* d_in, const int* in_sizes, int n_in,
                              void* d_out, int out_size, void* d_ws, size_t ws_size,
                              hipStream_t stream) {
  const float* x = (const float*)d_in[0];
  const float* ve = (const float*)d_in[1];
  const float* cosT = (const float*)d_in[2];
  const float* sinT = (const float*)d_in[3];
  const float* wq = (const float*)d_in[4];
  const float* wk = (const float*)d_in[5];
  const float* wv = (const float*)d_in[6];
  const float* wo = (const float*)d_in[7];
  const float* wgate = (const float*)d_in[8];
  const int* winp = (const int*)d_in[9];
  float* out = (float*)d_out;
  char* ws = (char*)d_ws;

  const int B = 2, T = 2048;
  short* xb    = (short*)(ws);
  short* wqkvb = (short*)(ws + 16777216);
  short* wob   = (short*)(ws + 29360128);
  short* qkv   = (short*)(ws + 37748736);
  short* qpost = (short*)(ws + 62914560);
  short* kpost = (short*)(ws + 79691776);
  short* vpost = (short*)(ws + 83886080);
  short* ybuf  = (short*)(ws + 88080384);

  auto cvt = [&](const float* src, short* dst, int n) {
    cvt_f32_bf16<<<dim3((n / 4 + 255) / 256), dim3(256), 0, stream>>>(src, dst, n);
  };
  cvt(x, xb, B * T * 2048);
  cvt(wq, wqkvb, 2048 * 2048);
  cvt(wk, wqkvb + 2048 * 2048, 512 * 2048);
  cvt(wv, wqkvb + 2560 * 2048, 512 * 2048);
  cvt(wo, wob, 2048 * 2048);

  // QKV: M=4096 N=3072 K=2048 -> 16x24 = 384 blocks (%8==0)
  gemm_bt2<1><<<dim3(384), 512, 0, stream>>>(xb, wqkvb, qkv, 4096, 3072, 2048, 24);

  rope_rms_qk<<<dim3(B * T * 20), 64, 0, stream>>>(qkv, cosT, sinT, qpost, kpost);
  v_gate<<<dim3(B * T * 4), 64, 0, stream>>>(qkv, x, ve, wgate, vpost);

  attn_sw2<<<dim3(512), 256, 0, stream>>>(qpost, kpost, vpost, ybuf, winp);

  // out-proj: M=4096 N=2048 K=2048 -> 16x16 = 256 blocks (%8==0)
  gemm_bt2<0><<<dim3(256), 512, 0, stream>>>(ybuf, wob, out, 4096, 2048, 2048, 16);
}

// Round 4
// 203.307 us; speedup vs baseline: 1.1730x; 1.0461x over previous
//
#include <hip/hip_runtime.h>
#include <hip/hip_bf16.h>

typedef __attribute__((ext_vector_type(8))) short short8_t;
typedef __attribute__((ext_vector_type(4))) float f32x4;
typedef __attribute__((ext_vector_type(16))) float f32x16;
using bf16 = __hip_bfloat16;

#define MFMA_BF16(A, B, C) __builtin_amdgcn_mfma_f32_16x16x32_bf16((A), (B), (C), 0, 0, 0)
#define MFMA32_BF16(A, B, C) __builtin_amdgcn_mfma_f32_32x32x16_bf16((A), (B), (C), 0, 0, 0)

#define GLD_LDS16(g, l)                                                        \
  __builtin_amdgcn_global_load_lds(                                           \
      (const __attribute__((address_space(1))) unsigned int*)(const void*)(g),\
      (__attribute__((address_space(3))) unsigned int*)(void*)(l), 16, 0, 0)

__device__ __forceinline__ float bits2f(short s) {
  union { unsigned int u; float f; } c;
  c.u = ((unsigned int)(unsigned short)s) << 16;
  return c.f;
}
__device__ __forceinline__ short f2bits(float f) {
  bf16 h = __float2bfloat16(f);
  return *reinterpret_cast<short*>(&h);
}
__device__ __forceinline__ unsigned pack2(float lo, float hi) {
  return ((unsigned)(unsigned short)f2bits(lo)) |
         (((unsigned)(unsigned short)f2bits(hi)) << 16);
}
__device__ __forceinline__ float exp2_(float x) {
#if __has_builtin(__builtin_amdgcn_exp2f)
  return __builtin_amdgcn_exp2f(x);
#else
  return exp2f(x);
#endif
}

// ---------------- fp32 -> bf16 convert ----------------
__global__ __launch_bounds__(256) void cvt_f32_bf16(const float* __restrict__ in,
                                                    short* __restrict__ out, int n) {
  int i = (blockIdx.x * 256 + threadIdx.x) * 4;
  if (i >= n) return;
  float4 v = *reinterpret_cast<const float4*>(in + i);
  short4 o;
  o.x = f2bits(v.x); o.y = f2bits(v.y); o.z = f2bits(v.z); o.w = f2bits(v.w);
  *reinterpret_cast<short4*>(out + i) = o;
}

// wq|wk|wv -> one contiguous bf16 buffer (3072x2048)
__global__ __launch_bounds__(256) void cvt_w3(const float* __restrict__ wq,
                                              const float* __restrict__ wk,
                                              const float* __restrict__ wv,
                                              short* __restrict__ out) {
  int i = (blockIdx.x * 256 + threadIdx.x) * 4;
  const float* src;
  int off;
  if (i < 4194304) { src = wq; off = i; }
  else if (i < 5242880) { src = wk; off = i - 4194304; }
  else { src = wv; off = i - 5242880; }
  float4 v = *reinterpret_cast<const float4*>(src + off);
  short4 o;
  o.x = f2bits(v.x); o.y = f2bits(v.y); o.z = f2bits(v.z); o.w = f2bits(v.w);
  *reinterpret_cast<short4*>(out + i) = o;
}

// ---------------- bf16 B^T GEMM v3: 3-buffer counted-vmcnt pipeline ----------------
// BM=256 BN=128 BK=32, 8 waves (2x4), 3 LDS buffers (72 KB, 2 blocks/CU).
// Stage distance 2: iter t issues tile t+2; s_waitcnt vmcnt(3) waits only tile
// t+1's loads (t+2's stay in flight) -> no vmcnt(0) drain in the main loop.
// Raw s_barrier via inline asm (no compiler-inserted drain). nwg%8==0 required.
template <int STORE_BF16>
__global__ __launch_bounds__(512, 4) void gemm_bt3(const short* __restrict__ A,
                                                   const short* __restrict__ Bt,
                                                   void* __restrict__ C,
                                                   int M, int N, int K, int NBN) {
  __shared__ __align__(16) short lds[3 * 12288];  // per buf: A 16KB + B 8KB
  const int nwg = gridDim.x;
  const int cpx = nwg >> 3;
  const int wg = ((int)blockIdx.x & 7) * cpx + ((int)blockIdx.x >> 3);
  const int m0 = (wg / NBN) * 256, n0 = (wg % NBN) * 128;

  const int tid = threadIdx.x, w = tid >> 6, lane = tid & 63;
  const int wr = w >> 2, wc = w & 3;
  const int rr = lane & 15, g = lane >> 4;

  // staging source decode for swizzle phys = ((row<<6)|(c<<4)|sub) ^ ((row&7)<<4)
  const int d = tid * 16;
  const int sr0 = ((d >> 6) & 1) ^ ((d >> 8) & 1);
  const int srow = ((d >> 7) << 1) | sr0;
  const int sc = ((d >> 4) & 3) ^ (srow & 3);
  const short* Asrc = A + (size_t)(m0 + srow) * K + sc * 8;
  const short* Bsrc = Bt + (size_t)(n0 + srow) * K + sc * 8;

  const int arow = wr * 128 + rr;
  const int abyte0 = ((arow << 6) | (g << 4)) ^ ((rr & 7) << 4);
  const int brow0 = wc * 32 + rr;
  const int bbyte0 = ((brow0 << 6) | (g << 4)) ^ ((rr & 7) << 4);

  f32x4 acc[8][2];
#pragma unroll
  for (int mi = 0; mi < 8; ++mi) {
    acc[mi][0] = (f32x4){0.f, 0.f, 0.f, 0.f};
    acc[mi][1] = (f32x4){0.f, 0.f, 0.f, 0.f};
  }

  const int ldst = w * 512;  // wave-uniform dest offset (shorts)
  const int nt = K >> 5;

#define STAGE3(t, base) do {                                                   \
    const short* a_ = Asrc + (size_t)(t) * 32;                                 \
    GLD_LDS16(a_, lds + (base) + ldst);                                        \
    GLD_LDS16(a_ + (size_t)128 * K, lds + (base) + 4096 + ldst);               \
    GLD_LDS16(Bsrc + (size_t)(t) * 32, lds + (base) + 8192 + ldst);            \
  } while (0)

  STAGE3(0, 0);
  STAGE3(1, 12288);
  asm volatile("s_waitcnt vmcnt(3)" ::: "memory");  // tile 0 ready
  asm volatile("s_barrier" ::: "memory");

  int c = 0;
  for (int t = 0; t < nt; ++t) {
    int cn = c + 12288; if (cn >= 36864) cn -= 36864;
    int cs = cn + 12288; if (cs >= 36864) cs -= 36864;
    bool more = (t + 2) < nt;
    if (more) STAGE3(t + 2, cs);  // buf cs held t-1, consumed at iter t-1

    const char* As_ = (const char*)(lds + c);
    const char* Bs_ = As_ + 16384;
    short8_t b0 = *(const short8_t*)(Bs_ + bbyte0);
    short8_t b1 = *(const short8_t*)(Bs_ + bbyte0 + 1024);
    __builtin_amdgcn_s_setprio(1);
#pragma unroll
    for (int mi = 0; mi < 8; ++mi) {
      short8_t a = *(const short8_t*)(As_ + abyte0 + mi * 1024);
      acc[mi][0] = MFMA_BF16(a, b0, acc[mi][0]);
      acc[mi][1] = MFMA_BF16(a, b1, acc[mi][1]);
    }
    __builtin_amdgcn_s_setprio(0);

    if (more)
      asm volatile("s_waitcnt vmcnt(3)" ::: "memory");  // t+1 landed; t+2 in flight
    else
      asm volatile("s_waitcnt vmcnt(0)" ::: "memory");  // tail drain
    asm volatile("s_barrier" ::: "memory");
    c = cn;
  }
#undef STAGE3

#pragma unroll
  for (int mi = 0; mi < 8; ++mi)
#pragma unroll
    for (int ni = 0; ni < 2; ++ni) {
      const int row = m0 + wr * 128 + mi * 16 + g * 4;
      const int col = n0 + wc * 32 + ni * 16 + rr;
#pragma unroll
      for (int j = 0; j < 4; ++j) {
        float v = acc[mi][ni][j];
        if (STORE_BF16)
          reinterpret_cast<short*>(C)[(size_t)(row + j) * N + col] = f2bits(v);
        else
          reinterpret_cast<float*>(C)[(size_t)(row + j) * N + col] = v;
      }
    }
}

// ---------------- RoPE + RMS for q and k (4 units / 256-thread block) ----------------
__global__ __launch_bounds__(256) void rope_rms_qk(const short* __restrict__ qkv,
                                                   const float* __restrict__ cosT,
                                                   const float* __restrict__ sinT,
                                                   short* __restrict__ qO,
                                                   short* __restrict__ kO) {
  const int T = 2048;
  int unit = blockIdx.x * 4 + (threadIdx.x >> 6);
  int lane = threadIdx.x & 63;
  int hh = unit % 20;
  int t = (unit / 20) % T;
  int b = unit / (20 * T);
  int col = hh < 16 ? hh * 128 : 2048 + (hh - 16) * 128;
  const short* src = qkv + (size_t)(b * T + t) * 3072 + col;
  float t1 = bits2f(src[lane]), t2 = bits2f(src[lane + 64]);
  float c = cosT[t * 64 + lane], s = sinT[t * 64 + lane];
  float o1 = t1 * c + t2 * s;
  float o2 = t2 * c - t1 * s;
  float ss = o1 * o1 + o2 * o2;
#pragma unroll
  for (int o = 1; o < 64; o <<= 1) ss += __shfl_xor(ss, o, 64);
  float r = rsqrtf(ss * (1.f / 128.f) + 1.1920929e-07f);
  short* dst;
  if (hh < 16) {
    r *= 0.08838834764831845f * 1.4426950408889634f;  // 1/sqrt(128) * log2e
    dst = qO + ((size_t)(b * 16 + hh) * T + t) * 128;
  } else {
    dst = kO + ((size_t)(b * 4 + (hh - 16)) * T + t) * 128;
  }
  dst[lane] = f2bits(o1 * r);
  dst[lane + 64] = f2bits(o2 * r);
}

// ---------------- v = v + 2*sigmoid(x[:32]@wgate^T) * ve (4 units / block) ----------------
__global__ __launch_bounds__(256) void v_gate(const short* __restrict__ qkv,
                                              const float* __restrict__ x,
                                              const float* __restrict__ ve,
                                              const float* __restrict__ wgate,
                                              short* __restrict__ vO) {
  const int T = 2048;
  int unit = blockIdx.x * 4 + (threadIdx.x >> 6);
  int lane = threadIdx.x & 63;
  int kv = unit & 3;
  int t = (unit >> 2) % T;
  int b = unit / (4 * T);
  size_t m = (size_t)b * T + t;
  float z = 0.f;
  if (lane < 32) z = x[m * 2048 + lane] * wgate[kv * 32 + lane];
#pragma unroll
  for (int o = 1; o < 64; o <<= 1) z += __shfl_xor(z, o, 64);
  float gate = 2.f / (1.f + __expf(-z));
  const short* vsrc = qkv + m * 3072 + 2560 + kv * 128;
  const float* vesrc = ve + m * 512 + kv * 128;
  short* dst = vO + ((size_t)(b * 4 + kv) * T + t) * 128;
  dst[lane] = f2bits(bits2f(vsrc[lane]) + gate * vesrc[lane]);
  dst[lane + 64] = f2bits(bits2f(vsrc[lane + 64]) + gate * vesrc[lane + 64]);
}

// ---------------- sliding-window flash attention, swapped-QK 32x32 ----------------
__global__ __launch_bounds__(256) void attn_sw2(const short* __restrict__ Q,
                                                const short* __restrict__ K,
                                                const short* __restrict__ V,
                                                short* __restrict__ Y,
                                                const int* __restrict__ winp) {
  const int T = 2048, H = 16;
  const int win = *winp;
  int combo = blockIdx.x & 7;          // (b,kvh) -> XCD pin
  int j = blockIdx.x >> 3;
  int b = combo >> 2, kvh = combo & 3;
  int h = kvh * 4 + (j & 3);
  int q0 = (j >> 2) * 128;

  __shared__ __align__(16) short Ks[64 * 128];
  __shared__ __align__(16) short Vs[128 * 64];

  int tid = threadIdx.x, w = tid >> 6, lane = tid & 63;
  int ql = lane & 31, hi = lane >> 5;
  int qrow = q0 + w * 32 + ql;

  const short* qbase = Q + ((size_t)(b * H + h) * T + qrow) * 128;
  short8_t qf[8];
#pragma unroll
  for (int ks = 0; ks < 8; ++ks)
    qf[ks] = *reinterpret_cast<const short8_t*>(qbase + ks * 16 + hi * 8);

  const short* kbase = K + (size_t)(b * 4 + kvh) * T * 128;
  const short* vbase = V + (size_t)(b * 4 + kvh) * T * 128;

  f32x16 acc[4];
#pragma unroll
  for (int dt = 0; dt < 4; ++dt)
#pragma unroll
    for (int r = 0; r < 16; ++r) acc[dt][r] = 0.f;
  float mreg = -1e30f, lsum = 0.f;

  int vkey = tid >> 2;
  int vdc = tid & 3;

  int lo = q0 - win + 1;
  if (lo < 0) lo = 0;
  lo &= ~63;
  int qmin = q0 + w * 32, qmax = qmin + 31;

  for (int kc = lo; kc < q0 + 128; kc += 64) {
    __syncthreads();
#pragma unroll
    for (int r = 0; r < 4; ++r) {
      int slot = (r * 4 + w) * 64 + lane;
      int krow = slot >> 4;
      int c16 = (slot & 15) ^ (krow & 7);
      GLD_LDS16(kbase + (size_t)(kc + krow) * 128 + c16 * 8,
                (char*)Ks + (r * 4 + w) * 1024);
    }
    {
      const short* vsrc = vbase + (size_t)(kc + vkey) * 128 + vdc * 32;
      short8_t vv[4];
#pragma unroll
      for (int q2 = 0; q2 < 4; ++q2)
        vv[q2] = *reinterpret_cast<const short8_t*>(vsrc + q2 * 8);
#pragma unroll
      for (int i = 0; i < 32; ++i) {
        int dd = vdc * 32 + i;
        int byte = dd * 128 + vkey * 2;
        byte ^= ((i & 7) ^ vdc) << 4;
        *reinterpret_cast<short*>((char*)Vs + byte) = vv[i >> 3][i & 7];
      }
    }
    __syncthreads();

    bool active = (kc <= qmax) && (kc + 63 >= qmin - win + 1);
    if (active) {
      f32x16 sA[2];
#pragma unroll
      for (int r = 0; r < 16; ++r) { sA[0][r] = 0.f; sA[1][r] = 0.f; }
#pragma unroll
      for (int kt = 0; kt < 2; ++kt) {
        int kr = kt * 32 + ql;
#pragma unroll
        for (int ks = 0; ks < 8; ++ks) {
          int byte = kr * 256 + (((ks * 2 + hi) ^ (kr & 7)) << 4);
          short8_t kf = *reinterpret_cast<const short8_t*>((char*)Ks + byte);
          sA[kt] = MFMA32_BF16(kf, qf[ks], sA[kt]);
        }
      }
      float pmax = -1e30f;
#pragma unroll
      for (int kt = 0; kt < 2; ++kt)
#pragma unroll
        for (int r = 0; r < 16; ++r) {
          int key = kc + kt * 32 + (r & 3) + 8 * (r >> 2) + 4 * hi;
          float sv = sA[kt][r];
          sv = ((unsigned)(qrow - key) < (unsigned)win) ? sv : -1e30f;
          sA[kt][r] = sv;
          pmax = fmaxf(pmax, sv);
        }
      pmax = fmaxf(pmax, __shfl_xor(pmax, 32, 64));
      float mn = fmaxf(mreg, pmax);
      float corr = exp2_(mreg - mn);
      mreg = mn;
      float rs = 0.f;
#pragma unroll
      for (int kt = 0; kt < 2; ++kt)
#pragma unroll
        for (int r = 0; r < 16; ++r) {
          float p = exp2_(sA[kt][r] - mn);
          sA[kt][r] = p;
          rs += p;
        }
      rs += __shfl_xor(rs, 32, 64);
      lsum = lsum * corr + rs;
#pragma unroll
      for (int dt = 0; dt < 4; ++dt)
#pragma unroll
        for (int r = 0; r < 16; ++r) acc[dt][r] *= corr;

#pragma unroll
      for (int kt = 0; kt < 2; ++kt)
#pragma unroll
        for (int s = 0; s < 2; ++s) {
          unsigned a = pack2(sA[kt][8 * s + 0], sA[kt][8 * s + 1]);
          unsigned bb = pack2(sA[kt][8 * s + 2], sA[kt][8 * s + 3]);
          unsigned c = pack2(sA[kt][8 * s + 4], sA[kt][8 * s + 5]);
          unsigned dd = pack2(sA[kt][8 * s + 6], sA[kt][8 * s + 7]);
          unsigned sa = __shfl_xor(a, 32, 64);
          unsigned sb = __shfl_xor(bb, 32, 64);
          unsigned sc2 = __shfl_xor(c, 32, 64);
          unsigned sd = __shfl_xor(dd, 32, 64);
          union { unsigned u[4]; short8_t s8; } pu;
          pu.u[0] = hi ? sc2 : a;
          pu.u[1] = hi ? sd : bb;
          pu.u[2] = hi ? c : sa;
          pu.u[3] = hi ? dd : sb;
          int kb = kt * 64 + s * 32 + hi * 16;
#pragma unroll
          for (int dt = 0; dt < 4; ++dt) {
            int drow = dt * 32 + ql;
            int byte = drow * 128 + kb;
            byte ^= ((drow & 7) ^ dt) << 4;
            short8_t vf = *reinterpret_cast<const short8_t*>((char*)Vs + byte);
            acc[dt] = MFMA32_BF16(vf, pu.s8, acc[dt]);
          }
        }
    }
  }

  float rinv = 1.f / lsum;
  short* ybase = Y + ((size_t)(b * T + qrow) * H + h) * 128;
#pragma unroll
  for (int dt = 0; dt < 4; ++dt)
#pragma unroll
    for (int g2 = 0; g2 < 4; ++g2) {
      short4 o;
      o.x = f2bits(acc[dt][g2 * 4 + 0] * rinv);
      o.y = f2bits(acc[dt][g2 * 4 + 1] * rinv);
      o.z = f2bits(acc[dt][g2 * 4 + 2] * rinv);
      o.w = f2bits(acc[dt][g2 * 4 + 3] * rinv);
      *reinterpret_cast<short4*>(ybase + dt * 32 + 8 * g2 + 4 * hi) = o;
    }
}

// ---------------- launcher ----------------
extern "C" void kernel_launch(void* const* d_in, const int* in_sizes, int n_in,
                              void* d_out, int out_size, void* d_ws, size_t ws_size,
                              hipStream_t stream) {
  const float* x = (const float*)d_in[0];
  const float* ve = (const float*)d_in[1];
  const float* cosT = (const float*)d_in[2];
  const float* sinT = (const float*)d_in[3];
  const float* wq = (const float*)d_in[4];
  const float* wk = (const float*)d_in[5];
  const float* wv = (const float*)d_in[6];
  const float* wo = (const float*)d_in[7];
  const float* wgate = (const float*)d_in[8];
  const int* winp = (const int*)d_in[9];
  float* out = (float*)d_out;
  char* ws = (char*)d_ws;

  const int B = 2, T = 2048;
  short* xb    = (short*)(ws);
  short* wqkvb = (short*)(ws + 16777216);
  short* wob   = (short*)(ws + 29360128);
  short* qkv   = (short*)(ws + 37748736);
  short* qpost = (short*)(ws + 62914560);
  short* kpost = (short*)(ws + 79691776);
  short* vpost = (short*)(ws + 83886080);
  short* ybuf  = (short*)(ws + 88080384);

  cvt_f32_bf16<<<dim3(8192), 256, 0, stream>>>(x, xb, B * T * 2048);
  cvt_w3<<<dim3(6144), 256, 0, stream>>>(wq, wk, wv, wqkvb);
  cvt_f32_bf16<<<dim3(4096), 256, 0, stream>>>(wo, wob, 2048 * 2048);

  // QKV: M=4096 N=3072 K=2048 -> 16x24 = 384 blocks (%8==0)
  gemm_bt3<1><<<dim3(384), 512, 0, stream>>>(xb, wqkvb, qkv, 4096, 3072, 2048, 24);

  rope_rms_qk<<<dim3(B * T * 20 / 4), 256, 0, stream>>>(qkv, cosT, sinT, qpost, kpost);
  v_gate<<<dim3(B * T), 256, 0, stream>>>(qkv, x, ve, wgate, vpost);

  attn_sw2<<<dim3(512), 256, 0, stream>>>(qpost, kpost, vpost, ybuf, winp);

  // out-proj: M=4096 N=2048 K=2048 -> 16x16 = 256 blocks (%8==0)
  gemm_bt3<0><<<dim3(256), 512, 0, stream>>>(ybuf, wob, out, 4096, 2048, 2048, 16);
}

// Round 5
// 196.645 us; speedup vs baseline: 1.2128x; 1.0339x over previous
//
#include <hip/hip_runtime.h>
#include <hip/hip_bf16.h>

typedef __attribute__((ext_vector_type(8))) short short8_t;
typedef __attribute__((ext_vector_type(4))) float f32x4;
typedef __attribute__((ext_vector_type(16))) float f32x16;
using bf16 = __hip_bfloat16;

#define MFMA_BF16(A, B, C) __builtin_amdgcn_mfma_f32_16x16x32_bf16((A), (B), (C), 0, 0, 0)
#define MFMA32_BF16(A, B, C) __builtin_amdgcn_mfma_f32_32x32x16_bf16((A), (B), (C), 0, 0, 0)

#define GLD_LDS16(g, l)                                                        \
  __builtin_amdgcn_global_load_lds(                                           \
      (const __attribute__((address_space(1))) unsigned int*)(const void*)(g),\
      (__attribute__((address_space(3))) unsigned int*)(void*)(l), 16, 0, 0)

__device__ __forceinline__ float bits2f(short s) {
  union { unsigned int u; float f; } c;
  c.u = ((unsigned int)(unsigned short)s) << 16;
  return c.f;
}
__device__ __forceinline__ short f2bits(float f) {
  bf16 h = __float2bfloat16(f);
  return *reinterpret_cast<short*>(&h);
}
__device__ __forceinline__ unsigned pack2(float lo, float hi) {
  return ((unsigned)(unsigned short)f2bits(lo)) |
         (((unsigned)(unsigned short)f2bits(hi)) << 16);
}
__device__ __forceinline__ float exp2_(float x) {
#if __has_builtin(__builtin_amdgcn_exp2f)
  return __builtin_amdgcn_exp2f(x);
#else
  return exp2f(x);
#endif
}

// ---------------- fp32 -> bf16 convert ----------------
__global__ __launch_bounds__(256) void cvt_f32_bf16(const float* __restrict__ in,
                                                    short* __restrict__ out, int n) {
  int i = (blockIdx.x * 256 + threadIdx.x) * 4;
  if (i >= n) return;
  float4 v = *reinterpret_cast<const float4*>(in + i);
  short4 o;
  o.x = f2bits(v.x); o.y = f2bits(v.y); o.z = f2bits(v.z); o.w = f2bits(v.w);
  *reinterpret_cast<short4*>(out + i) = o;
}

// wq|wk|wv -> one contiguous bf16 buffer (3072x2048)
__global__ __launch_bounds__(256) void cvt_w3(const float* __restrict__ wq,
                                              const float* __restrict__ wk,
                                              const float* __restrict__ wv,
                                              short* __restrict__ out) {
  int i = (blockIdx.x * 256 + threadIdx.x) * 4;
  const float* src;
  int off;
  if (i < 4194304) { src = wq; off = i; }
  else if (i < 5242880) { src = wk; off = i - 4194304; }
  else { src = wv; off = i - 5242880; }
  float4 v = *reinterpret_cast<const float4*>(src + off);
  short4 o;
  o.x = f2bits(v.x); o.y = f2bits(v.y); o.z = f2bits(v.z); o.w = f2bits(v.w);
  *reinterpret_cast<short4*>(out + i) = o;
}

// ---------------- bf16 B^T GEMM v4: 128x128 tile, BK=64, 4 waves (2x2) ----------------
// Per-wave output 64x64 (32 FLOP per LDS byte vs 26 of the BK=32 form).
// Double-buffered 64 KB LDS -> 2 blocks/CU. All 8 stage loads front-loaded at
// iter top (aged ~full K-tile at the drain); ONE vmcnt(0)+s_barrier per 64-K.
// 128-B LDS rows + 8-row granule-XOR swizzle = bank-balanced ds_read_b128.
// nwg%8==0 required (XCD chunk swizzle).
template <int STORE_BF16>
__global__ __launch_bounds__(256, 2) void gemm_bt4(const short* __restrict__ A,
                                                   const short* __restrict__ Bt,
                                                   void* __restrict__ C,
                                                   int M, int N, int K, int NBN) {
  __shared__ __align__(16) short lds[2 * 16384];  // per buf: A 16KB + B 16KB
  const int nwg = gridDim.x;
  const int cpx = nwg >> 3;
  const int wg = ((int)blockIdx.x & 7) * cpx + ((int)blockIdx.x >> 3);
  const int m0 = (wg / NBN) * 128, n0 = (wg % NBN) * 128;

  const int tid = threadIdx.x, w = tid >> 6, lane = tid & 63;
  const int wr = w >> 1, wc = w & 1;
  const int rr = lane & 15, g = lane >> 4;

  // staging: round r stages rows r*32 + (tid>>3), granule gc (inverse swizzle)
  const int srow = tid >> 3;
  const int gc = (tid & 7) ^ (srow & 7);
  const short* Asrc = A + (size_t)(m0 + srow) * K + gc * 8;
  const short* Bsrc = Bt + (size_t)(n0 + srow) * K + gc * 8;
  const size_t rstep = (size_t)32 * K;  // 32 rows per 4KB staging round
  const int dofs = tid * 16;            // linear dest byte within a round

  // ds_read byte bases within buffer: phys = ((row<<7)|(gcol<<4)) ^ ((row&7)<<4)
  const int abase = (((wr * 64 + rr) << 7) | (g << 4)) ^ ((rr & 7) << 4);
  const int bbase = ((((wc * 64 + rr) << 7) | (g << 4)) ^ ((rr & 7) << 4)) + 16384;

  f32x4 acc[4][4];
#pragma unroll
  for (int mi = 0; mi < 4; ++mi)
#pragma unroll
    for (int ni = 0; ni < 4; ++ni) acc[mi][ni] = (f32x4){0.f, 0.f, 0.f, 0.f};

  const int nt = K >> 6;

#define STAGE4(t, bufbyte) do {                                                \
    const short* a_ = Asrc + (size_t)(t) * 64;                                 \
    const short* b_ = Bsrc + (size_t)(t) * 64;                                 \
    char* la_ = (char*)lds + (bufbyte) + dofs;                                 \
    GLD_LDS16(a_,             la_);                                            \
    GLD_LDS16(a_ + rstep,     la_ + 4096);                                     \
    GLD_LDS16(a_ + 2 * rstep, la_ + 8192);                                     \
    GLD_LDS16(a_ + 3 * rstep, la_ + 12288);                                    \
    GLD_LDS16(b_,             la_ + 16384);                                    \
    GLD_LDS16(b_ + rstep,     la_ + 20480);                                    \
    GLD_LDS16(b_ + 2 * rstep, la_ + 24576);                                    \
    GLD_LDS16(b_ + 3 * rstep, la_ + 28672);                                    \
  } while (0)

  // prologue: K-tile 0 -> buf 0
  STAGE4(0, 0);
  asm volatile("s_waitcnt vmcnt(0)" ::: "memory");
  asm volatile("s_barrier" ::: "memory");

  int cur = 0;
  for (int t = 0; t < nt; ++t) {
    if (t + 1 < nt) STAGE4(t + 1, cur ^ 32768);  // front-loaded prefetch
    const char* bufp = (const char*)lds + cur;
#pragma unroll
    for (int kk = 0; kk < 2; ++kk) {
      const int ko = kk * 64;  // kk flips bit 6 inside the swizzle field
      short8_t a0 = *(const short8_t*)(bufp + ((abase ^ ko)));
      short8_t a1 = *(const short8_t*)(bufp + ((abase ^ ko) + 2048));
      short8_t a2 = *(const short8_t*)(bufp + ((abase ^ ko) + 4096));
      short8_t a3 = *(const short8_t*)(bufp + ((abase ^ ko) + 6144));
      short8_t b0 = *(const short8_t*)(bufp + ((bbase ^ ko)));
      short8_t b1 = *(const short8_t*)(bufp + ((bbase ^ ko) + 2048));
      short8_t b2 = *(const short8_t*)(bufp + ((bbase ^ ko) + 4096));
      short8_t b3 = *(const short8_t*)(bufp + ((bbase ^ ko) + 6144));
      __builtin_amdgcn_s_setprio(1);
      acc[0][0] = MFMA_BF16(a0, b0, acc[0][0]);
      acc[0][1] = MFMA_BF16(a0, b1, acc[0][1]);
      acc[0][2] = MFMA_BF16(a0, b2, acc[0][2]);
      acc[0][3] = MFMA_BF16(a0, b3, acc[0][3]);
      acc[1][0] = MFMA_BF16(a1, b0, acc[1][0]);
      acc[1][1] = MFMA_BF16(a1, b1, acc[1][1]);
      acc[1][2] = MFMA_BF16(a1, b2, acc[1][2]);
      acc[1][3] = MFMA_BF16(a1, b3, acc[1][3]);
      acc[2][0] = MFMA_BF16(a2, b0, acc[2][0]);
      acc[2][1] = MFMA_BF16(a2, b1, acc[2][1]);
      acc[2][2] = MFMA_BF16(a2, b2, acc[2][2]);
      acc[2][3] = MFMA_BF16(a2, b3, acc[2][3]);
      acc[3][0] = MFMA_BF16(a3, b0, acc[3][0]);
      acc[3][1] = MFMA_BF16(a3, b1, acc[3][1]);
      acc[3][2] = MFMA_BF16(a3, b2, acc[3][2]);
      acc[3][3] = MFMA_BF16(a3, b3, acc[3][3]);
      __builtin_amdgcn_s_setprio(0);
    }
    if (t + 1 < nt) {
      asm volatile("s_waitcnt vmcnt(0)" ::: "memory");  // aged ~1 K-tile
      asm volatile("s_barrier" ::: "memory");
    }
    cur ^= 32768;
  }
#undef STAGE4

#pragma unroll
  for (int mi = 0; mi < 4; ++mi)
#pragma unroll
    for (int ni = 0; ni < 4; ++ni) {
      const int row = m0 + wr * 64 + mi * 16 + g * 4;
      const int col = n0 + wc * 64 + ni * 16 + rr;
#pragma unroll
      for (int j = 0; j < 4; ++j) {
        float v = acc[mi][ni][j];
        if (STORE_BF16)
          reinterpret_cast<short*>(C)[(size_t)(row + j) * N + col] = f2bits(v);
        else
          reinterpret_cast<float*>(C)[(size_t)(row + j) * N + col] = v;
      }
    }
}

// ---------------- RoPE + RMS for q and k (4 units / 256-thread block) ----------------
__global__ __launch_bounds__(256) void rope_rms_qk(const short* __restrict__ qkv,
                                                   const float* __restrict__ cosT,
                                                   const float* __restrict__ sinT,
                                                   short* __restrict__ qO,
                                                   short* __restrict__ kO) {
  const int T = 2048;
  int unit = blockIdx.x * 4 + (threadIdx.x >> 6);
  int lane = threadIdx.x & 63;
  int hh = unit % 20;
  int t = (unit / 20) % T;
  int b = unit / (20 * T);
  int col = hh < 16 ? hh * 128 : 2048 + (hh - 16) * 128;
  const short* src = qkv + (size_t)(b * T + t) * 3072 + col;
  float t1 = bits2f(src[lane]), t2 = bits2f(src[lane + 64]);
  float c = cosT[t * 64 + lane], s = sinT[t * 64 + lane];
  float o1 = t1 * c + t2 * s;
  float o2 = t2 * c - t1 * s;
  float ss = o1 * o1 + o2 * o2;
#pragma unroll
  for (int o = 1; o < 64; o <<= 1) ss += __shfl_xor(ss, o, 64);
  float r = rsqrtf(ss * (1.f / 128.f) + 1.1920929e-07f);
  short* dst;
  if (hh < 16) {
    r *= 0.08838834764831845f * 1.4426950408889634f;  // 1/sqrt(128) * log2e
    dst = qO + ((size_t)(b * 16 + hh) * T + t) * 128;
  } else {
    dst = kO + ((size_t)(b * 4 + (hh - 16)) * T + t) * 128;
  }
  dst[lane] = f2bits(o1 * r);
  dst[lane + 64] = f2bits(o2 * r);
}

// ---------------- v = v + 2*sigmoid(x[:32]@wgate^T) * ve (4 units / block) ----------------
__global__ __launch_bounds__(256) void v_gate(const short* __restrict__ qkv,
                                              const float* __restrict__ x,
                                              const float* __restrict__ ve,
                                              const float* __restrict__ wgate,
                                              short* __restrict__ vO) {
  const int T = 2048;
  int unit = blockIdx.x * 4 + (threadIdx.x >> 6);
  int lane = threadIdx.x & 63;
  int kv = unit & 3;
  int t = (unit >> 2) % T;
  int b = unit / (4 * T);
  size_t m = (size_t)b * T + t;
  float z = 0.f;
  if (lane < 32) z = x[m * 2048 + lane] * wgate[kv * 32 + lane];
#pragma unroll
  for (int o = 1; o < 64; o <<= 1) z += __shfl_xor(z, o, 64);
  float gate = 2.f / (1.f + __expf(-z));
  const short* vsrc = qkv + m * 3072 + 2560 + kv * 128;
  const float* vesrc = ve + m * 512 + kv * 128;
  short* dst = vO + ((size_t)(b * 4 + kv) * T + t) * 128;
  dst[lane] = f2bits(bits2f(vsrc[lane]) + gate * vesrc[lane]);
  dst[lane + 64] = f2bits(bits2f(vsrc[lane + 64]) + gate * vesrc[lane + 64]);
}

// ---------------- sliding-window flash attention, swapped-QK 32x32 ----------------
__global__ __launch_bounds__(256) void attn_sw2(const short* __restrict__ Q,
                                                const short* __restrict__ K,
                                                const short* __restrict__ V,
                                                short* __restrict__ Y,
                                                const int* __restrict__ winp) {
  const int T = 2048, H = 16;
  const int win = *winp;
  int combo = blockIdx.x & 7;          // (b,kvh) -> XCD pin
  int j = blockIdx.x >> 3;
  int b = combo >> 2, kvh = combo & 3;
  int h = kvh * 4 + (j & 3);
  int q0 = (j >> 2) * 128;

  __shared__ __align__(16) short Ks[64 * 128];
  __shared__ __align__(16) short Vs[128 * 64];

  int tid = threadIdx.x, w = tid >> 6, lane = tid & 63;
  int ql = lane & 31, hi = lane >> 5;
  int qrow = q0 + w * 32 + ql;

  const short* qbase = Q + ((size_t)(b * H + h) * T + qrow) * 128;
  short8_t qf[8];
#pragma unroll
  for (int ks = 0; ks < 8; ++ks)
    qf[ks] = *reinterpret_cast<const short8_t*>(qbase + ks * 16 + hi * 8);

  const short* kbase = K + (size_t)(b * 4 + kvh) * T * 128;
  const short* vbase = V + (size_t)(b * 4 + kvh) * T * 128;

  f32x16 acc[4];
#pragma unroll
  for (int dt = 0; dt < 4; ++dt)
#pragma unroll
    for (int r = 0; r < 16; ++r) acc[dt][r] = 0.f;
  float mreg = -1e30f, lsum = 0.f;

  int vkey = tid >> 2;
  int vdc = tid & 3;

  int lo = q0 - win + 1;
  if (lo < 0) lo = 0;
  lo &= ~63;
  int qmin = q0 + w * 32, qmax = qmin + 31;

  for (int kc = lo; kc < q0 + 128; kc += 64) {
    __syncthreads();
#pragma unroll
    for (int r = 0; r < 4; ++r) {
      int slot = (r * 4 + w) * 64 + lane;
      int krow = slot >> 4;
      int c16 = (slot & 15) ^ (krow & 7);
      GLD_LDS16(kbase + (size_t)(kc + krow) * 128 + c16 * 8,
                (char*)Ks + (r * 4 + w) * 1024);
    }
    {
      const short* vsrc = vbase + (size_t)(kc + vkey) * 128 + vdc * 32;
      short8_t vv[4];
#pragma unroll
      for (int q2 = 0; q2 < 4; ++q2)
        vv[q2] = *reinterpret_cast<const short8_t*>(vsrc + q2 * 8);
#pragma unroll
      for (int i = 0; i < 32; ++i) {
        int dd = vdc * 32 + i;
        int byte = dd * 128 + vkey * 2;
        byte ^= ((i & 7) ^ vdc) << 4;
        *reinterpret_cast<short*>((char*)Vs + byte) = vv[i >> 3][i & 7];
      }
    }
    __syncthreads();

    bool active = (kc <= qmax) && (kc + 63 >= qmin - win + 1);
    if (active) {
      f32x16 sA[2];
#pragma unroll
      for (int r = 0; r < 16; ++r) { sA[0][r] = 0.f; sA[1][r] = 0.f; }
#pragma unroll
      for (int kt = 0; kt < 2; ++kt) {
        int kr = kt * 32 + ql;
#pragma unroll
        for (int ks = 0; ks < 8; ++ks) {
          int byte = kr * 256 + (((ks * 2 + hi) ^ (kr & 7)) << 4);
          short8_t kf = *reinterpret_cast<const short8_t*>((char*)Ks + byte);
          sA[kt] = MFMA32_BF16(kf, qf[ks], sA[kt]);
        }
      }
      float pmax = -1e30f;
#pragma unroll
      for (int kt = 0; kt < 2; ++kt)
#pragma unroll
        for (int r = 0; r < 16; ++r) {
          int key = kc + kt * 32 + (r & 3) + 8 * (r >> 2) + 4 * hi;
          float sv = sA[kt][r];
          sv = ((unsigned)(qrow - key) < (unsigned)win) ? sv : -1e30f;
          sA[kt][r] = sv;
          pmax = fmaxf(pmax, sv);
        }
      pmax = fmaxf(pmax, __shfl_xor(pmax, 32, 64));
      float mn = fmaxf(mreg, pmax);
      float corr = exp2_(mreg - mn);
      mreg = mn;
      float rs = 0.f;
#pragma unroll
      for (int kt = 0; kt < 2; ++kt)
#pragma unroll
        for (int r = 0; r < 16; ++r) {
          float p = exp2_(sA[kt][r] - mn);
          sA[kt][r] = p;
          rs += p;
        }
      rs += __shfl_xor(rs, 32, 64);
      lsum = lsum * corr + rs;
#pragma unroll
      for (int dt = 0; dt < 4; ++dt)
#pragma unroll
        for (int r = 0; r < 16; ++r) acc[dt][r] *= corr;

#pragma unroll
      for (int kt = 0; kt < 2; ++kt)
#pragma unroll
        for (int s = 0; s < 2; ++s) {
          unsigned a = pack2(sA[kt][8 * s + 0], sA[kt][8 * s + 1]);
          unsigned bb = pack2(sA[kt][8 * s + 2], sA[kt][8 * s + 3]);
          unsigned c = pack2(sA[kt][8 * s + 4], sA[kt][8 * s + 5]);
          unsigned dd = pack2(sA[kt][8 * s + 6], sA[kt][8 * s + 7]);
          unsigned sa = __shfl_xor(a, 32, 64);
          unsigned sb = __shfl_xor(bb, 32, 64);
          unsigned sc2 = __shfl_xor(c, 32, 64);
          unsigned sd = __shfl_xor(dd, 32, 64);
          union { unsigned u[4]; short8_t s8; } pu;
          pu.u[0] = hi ? sc2 : a;
          pu.u[1] = hi ? sd : bb;
          pu.u[2] = hi ? c : sa;
          pu.u[3] = hi ? dd : sb;
          int kb = kt * 64 + s * 32 + hi * 16;
#pragma unroll
          for (int dt = 0; dt < 4; ++dt) {
            int drow = dt * 32 + ql;
            int byte = drow * 128 + kb;
            byte ^= ((drow & 7) ^ dt) << 4;
            short8_t vf = *reinterpret_cast<const short8_t*>((char*)Vs + byte);
            acc[dt] = MFMA32_BF16(vf, pu.s8, acc[dt]);
          }
        }
    }
  }

  float rinv = 1.f / lsum;
  short* ybase = Y + ((size_t)(b * T + qrow) * H + h) * 128;
#pragma unroll
  for (int dt = 0; dt < 4; ++dt)
#pragma unroll
    for (int g2 = 0; g2 < 4; ++g2) {
      short4 o;
      o.x = f2bits(acc[dt][g2 * 4 + 0] * rinv);
      o.y = f2bits(acc[dt][g2 * 4 + 1] * rinv);
      o.z = f2bits(acc[dt][g2 * 4 + 2] * rinv);
      o.w = f2bits(acc[dt][g2 * 4 + 3] * rinv);
      *reinterpret_cast<short4*>(ybase + dt * 32 + 8 * g2 + 4 * hi) = o;
    }
}

// ---------------- launcher ----------------
extern "C" void kernel_launch(void* const* d_in, const int* in_sizes, int n_in,
                              void* d_out, int out_size, void* d_ws, size_t ws_size,
                              hipStream_t stream) {
  const float* x = (const float*)d_in[0];
  const float* ve = (const float*)d_in[1];
  const float* cosT = (const float*)d_in[2];
  const float* sinT = (const float*)d_in[3];
  const float* wq = (const float*)d_in[4];
  const float* wk = (const float*)d_in[5];
  const float* wv = (const float*)d_in[6];
  const float* wo = (const float*)d_in[7];
  const float* wgate = (const float*)d_in[8];
  const int* winp = (const int*)d_in[9];
  float* out = (float*)d_out;
  char* ws = (char*)d_ws;

  const int B = 2, T = 2048;
  short* xb    = (short*)(ws);
  short* wqkvb = (short*)(ws + 16777216);
  short* wob   = (short*)(ws + 29360128);
  short* qkv   = (short*)(ws + 37748736);
  short* qpost = (short*)(ws + 62914560);
  short* kpost = (short*)(ws + 79691776);
  short* vpost = (short*)(ws + 83886080);
  short* ybuf  = (short*)(ws + 88080384);

  cvt_f32_bf16<<<dim3(8192), 256, 0, stream>>>(x, xb, B * T * 2048);
  cvt_w3<<<dim3(6144), 256, 0, stream>>>(wq, wk, wv, wqkvb);
  cvt_f32_bf16<<<dim3(4096), 256, 0, stream>>>(wo, wob, 2048 * 2048);

  // QKV: M=4096 N=3072 K=2048 -> 32x24 = 768 blocks (%8==0)
  gemm_bt4<1><<<dim3(768), 256, 0, stream>>>(xb, wqkvb, qkv, 4096, 3072, 2048, 24);

  rope_rms_qk<<<dim3(B * T * 20 / 4), 256, 0, stream>>>(qkv, cosT, sinT, qpost, kpost);
  v_gate<<<dim3(B * T), 256, 0, stream>>>(qkv, x, ve, wgate, vpost);

  attn_sw2<<<dim3(512), 256, 0, stream>>>(qpost, kpost, vpost, ybuf, winp);

  // out-proj: M=4096 N=2048 K=2048 -> 32x16 = 512 blocks (%8==0)
  gemm_bt4<0><<<dim3(512), 256, 0, stream>>>(ybuf, wob, out, 4096, 2048, 2048, 16);
}

// Round 6
// 185.798 us; speedup vs baseline: 1.2836x; 1.0584x over previous
//
#include <hip/hip_runtime.h>
#include <hip/hip_bf16.h>

typedef __attribute__((ext_vector_type(8))) short short8_t;
typedef __attribute__((ext_vector_type(4))) float f32x4;
typedef __attribute__((ext_vector_type(16))) float f32x16;
using bf16 = __hip_bfloat16;

#define MFMA_BF16(A, B, C) __builtin_amdgcn_mfma_f32_16x16x32_bf16((A), (B), (C), 0, 0, 0)
#define MFMA32_BF16(A, B, C) __builtin_amdgcn_mfma_f32_32x32x16_bf16((A), (B), (C), 0, 0, 0)

#define GLD_LDS16(g, l)                                                        \
  __builtin_amdgcn_global_load_lds(                                           \
      (const __attribute__((address_space(1))) unsigned int*)(const void*)(g),\
      (__attribute__((address_space(3))) unsigned int*)(void*)(l), 16, 0, 0)

__device__ __forceinline__ float bits2f(short s) {
  union { unsigned int u; float f; } c;
  c.u = ((unsigned int)(unsigned short)s) << 16;
  return c.f;
}
__device__ __forceinline__ short f2bits(float f) {
  bf16 h = __float2bfloat16(f);
  return *reinterpret_cast<short*>(&h);
}
__device__ __forceinline__ unsigned pack2(float lo, float hi) {
  return ((unsigned)(unsigned short)f2bits(lo)) |
         (((unsigned)(unsigned short)f2bits(hi)) << 16);
}
__device__ __forceinline__ float exp2_(float x) {
#if __has_builtin(__builtin_amdgcn_exp2f)
  return __builtin_amdgcn_exp2f(x);
#else
  return exp2f(x);
#endif
}

// ---------------- fp32 -> bf16 convert ----------------
__global__ __launch_bounds__(256) void cvt_f32_bf16(const float* __restrict__ in,
                                                    short* __restrict__ out, int n) {
  int i = (blockIdx.x * 256 + threadIdx.x) * 4;
  if (i >= n) return;
  float4 v = *reinterpret_cast<const float4*>(in + i);
  short4 o;
  o.x = f2bits(v.x); o.y = f2bits(v.y); o.z = f2bits(v.z); o.w = f2bits(v.w);
  *reinterpret_cast<short4*>(out + i) = o;
}

// wq|wk|wv -> one contiguous bf16 buffer (3072x2048)
__global__ __launch_bounds__(256) void cvt_w3(const float* __restrict__ wq,
                                              const float* __restrict__ wk,
                                              const float* __restrict__ wv,
                                              short* __restrict__ out) {
  int i = (blockIdx.x * 256 + threadIdx.x) * 4;
  const float* src;
  int off;
  if (i < 4194304) { src = wq; off = i; }
  else if (i < 5242880) { src = wk; off = i - 4194304; }
  else { src = wv; off = i - 5242880; }
  float4 v = *reinterpret_cast<const float4*>(src + off);
  short4 o;
  o.x = f2bits(v.x); o.y = f2bits(v.y); o.z = f2bits(v.z); o.w = f2bits(v.w);
  *reinterpret_cast<short4*>(out + i) = o;
}

// ---------------- bf16 B^T GEMM v4: 128x128 tile, BK=64, 4 waves (2x2) ----------------
template <int STORE_BF16>
__global__ __launch_bounds__(256, 2) void gemm_bt4(const short* __restrict__ A,
                                                   const short* __restrict__ Bt,
                                                   void* __restrict__ C,
                                                   int M, int N, int K, int NBN) {
  __shared__ __align__(16) short lds[2 * 16384];  // per buf: A 16KB + B 16KB
  const int nwg = gridDim.x;
  const int cpx = nwg >> 3;
  const int wg = ((int)blockIdx.x & 7) * cpx + ((int)blockIdx.x >> 3);
  const int m0 = (wg / NBN) * 128, n0 = (wg % NBN) * 128;

  const int tid = threadIdx.x, w = tid >> 6, lane = tid & 63;
  const int wr = w >> 1, wc = w & 1;
  const int rr = lane & 15, g = lane >> 4;

  const int srow = tid >> 3;
  const int gc = (tid & 7) ^ (srow & 7);
  const short* Asrc = A + (size_t)(m0 + srow) * K + gc * 8;
  const short* Bsrc = Bt + (size_t)(n0 + srow) * K + gc * 8;
  const size_t rstep = (size_t)32 * K;
  const int dofs = tid * 16;

  const int abase = (((wr * 64 + rr) << 7) | (g << 4)) ^ ((rr & 7) << 4);
  const int bbase = ((((wc * 64 + rr) << 7) | (g << 4)) ^ ((rr & 7) << 4)) + 16384;

  f32x4 acc[4][4];
#pragma unroll
  for (int mi = 0; mi < 4; ++mi)
#pragma unroll
    for (int ni = 0; ni < 4; ++ni) acc[mi][ni] = (f32x4){0.f, 0.f, 0.f, 0.f};

  const int nt = K >> 6;

#define STAGE4(t, bufbyte) do {                                                \
    const short* a_ = Asrc + (size_t)(t) * 64;                                 \
    const short* b_ = Bsrc + (size_t)(t) * 64;                                 \
    char* la_ = (char*)lds + (bufbyte) + dofs;                                 \
    GLD_LDS16(a_,             la_);                                            \
    GLD_LDS16(a_ + rstep,     la_ + 4096);                                     \
    GLD_LDS16(a_ + 2 * rstep, la_ + 8192);                                     \
    GLD_LDS16(a_ + 3 * rstep, la_ + 12288);                                    \
    GLD_LDS16(b_,             la_ + 16384);                                    \
    GLD_LDS16(b_ + rstep,     la_ + 20480);                                    \
    GLD_LDS16(b_ + 2 * rstep, la_ + 24576);                                    \
    GLD_LDS16(b_ + 3 * rstep, la_ + 28672);                                    \
  } while (0)

  STAGE4(0, 0);
  asm volatile("s_waitcnt vmcnt(0)" ::: "memory");
  asm volatile("s_barrier" ::: "memory");

  int cur = 0;
  for (int t = 0; t < nt; ++t) {
    if (t + 1 < nt) STAGE4(t + 1, cur ^ 32768);
    const char* bufp = (const char*)lds + cur;
#pragma unroll
    for (int kk = 0; kk < 2; ++kk) {
      const int ko = kk * 64;
      short8_t a0 = *(const short8_t*)(bufp + ((abase ^ ko)));
      short8_t a1 = *(const short8_t*)(bufp + ((abase ^ ko) + 2048));
      short8_t a2 = *(const short8_t*)(bufp + ((abase ^ ko) + 4096));
      short8_t a3 = *(const short8_t*)(bufp + ((abase ^ ko) + 6144));
      short8_t b0 = *(const short8_t*)(bufp + ((bbase ^ ko)));
      short8_t b1 = *(const short8_t*)(bufp + ((bbase ^ ko) + 2048));
      short8_t b2 = *(const short8_t*)(bufp + ((bbase ^ ko) + 4096));
      short8_t b3 = *(const short8_t*)(bufp + ((bbase ^ ko) + 6144));
      __builtin_amdgcn_s_setprio(1);
      acc[0][0] = MFMA_BF16(a0, b0, acc[0][0]);
      acc[0][1] = MFMA_BF16(a0, b1, acc[0][1]);
      acc[0][2] = MFMA_BF16(a0, b2, acc[0][2]);
      acc[0][3] = MFMA_BF16(a0, b3, acc[0][3]);
      acc[1][0] = MFMA_BF16(a1, b0, acc[1][0]);
      acc[1][1] = MFMA_BF16(a1, b1, acc[1][1]);
      acc[1][2] = MFMA_BF16(a1, b2, acc[1][2]);
      acc[1][3] = MFMA_BF16(a1, b3, acc[1][3]);
      acc[2][0] = MFMA_BF16(a2, b0, acc[2][0]);
      acc[2][1] = MFMA_BF16(a2, b1, acc[2][1]);
      acc[2][2] = MFMA_BF16(a2, b2, acc[2][2]);
      acc[2][3] = MFMA_BF16(a2, b3, acc[2][3]);
      acc[3][0] = MFMA_BF16(a3, b0, acc[3][0]);
      acc[3][1] = MFMA_BF16(a3, b1, acc[3][1]);
      acc[3][2] = MFMA_BF16(a3, b2, acc[3][2]);
      acc[3][3] = MFMA_BF16(a3, b3, acc[3][3]);
      __builtin_amdgcn_s_setprio(0);
    }
    if (t + 1 < nt) {
      asm volatile("s_waitcnt vmcnt(0)" ::: "memory");
      asm volatile("s_barrier" ::: "memory");
    }
    cur ^= 32768;
  }
#undef STAGE4

#pragma unroll
  for (int mi = 0; mi < 4; ++mi)
#pragma unroll
    for (int ni = 0; ni < 4; ++ni) {
      const int row = m0 + wr * 64 + mi * 16 + g * 4;
      const int col = n0 + wc * 64 + ni * 16 + rr;
#pragma unroll
      for (int j = 0; j < 4; ++j) {
        float v = acc[mi][ni][j];
        if (STORE_BF16)
          reinterpret_cast<short*>(C)[(size_t)(row + j) * N + col] = f2bits(v);
        else
          reinterpret_cast<float*>(C)[(size_t)(row + j) * N + col] = v;
      }
    }
}

// ---------------- RoPE + RMS for q and k (4 units / 256-thread block) ----------------
__global__ __launch_bounds__(256) void rope_rms_qk(const short* __restrict__ qkv,
                                                   const float* __restrict__ cosT,
                                                   const float* __restrict__ sinT,
                                                   short* __restrict__ qO,
                                                   short* __restrict__ kO) {
  const int T = 2048;
  int unit = blockIdx.x * 4 + (threadIdx.x >> 6);
  int lane = threadIdx.x & 63;
  int hh = unit % 20;
  int t = (unit / 20) % T;
  int b = unit / (20 * T);
  int col = hh < 16 ? hh * 128 : 2048 + (hh - 16) * 128;
  const short* src = qkv + (size_t)(b * T + t) * 3072 + col;
  float t1 = bits2f(src[lane]), t2 = bits2f(src[lane + 64]);
  float c = cosT[t * 64 + lane], s = sinT[t * 64 + lane];
  float o1 = t1 * c + t2 * s;
  float o2 = t2 * c - t1 * s;
  float ss = o1 * o1 + o2 * o2;
#pragma unroll
  for (int o = 1; o < 64; o <<= 1) ss += __shfl_xor(ss, o, 64);
  float r = rsqrtf(ss * (1.f / 128.f) + 1.1920929e-07f);
  short* dst;
  if (hh < 16) {
    r *= 0.08838834764831845f * 1.4426950408889634f;  // 1/sqrt(128) * log2e
    dst = qO + ((size_t)(b * 16 + hh) * T + t) * 128;
  } else {
    dst = kO + ((size_t)(b * 4 + (hh - 16)) * T + t) * 128;
  }
  dst[lane] = f2bits(o1 * r);
  dst[lane + 64] = f2bits(o2 * r);
}

// ---------------- v = v + 2*sigmoid(x[:32]@wgate^T) * ve (4 units / block) ----------------
__global__ __launch_bounds__(256) void v_gate(const short* __restrict__ qkv,
                                              const float* __restrict__ x,
                                              const float* __restrict__ ve,
                                              const float* __restrict__ wgate,
                                              short* __restrict__ vO) {
  const int T = 2048;
  int unit = blockIdx.x * 4 + (threadIdx.x >> 6);
  int lane = threadIdx.x & 63;
  int kv = unit & 3;
  int t = (unit >> 2) % T;
  int b = unit / (4 * T);
  size_t m = (size_t)b * T + t;
  float z = 0.f;
  if (lane < 32) z = x[m * 2048 + lane] * wgate[kv * 32 + lane];
#pragma unroll
  for (int o = 1; o < 64; o <<= 1) z += __shfl_xor(z, o, 64);
  float gate = 2.f / (1.f + __expf(-z));
  const short* vsrc = qkv + m * 3072 + 2560 + kv * 128;
  const float* vesrc = ve + m * 512 + kv * 128;
  short* dst = vO + ((size_t)(b * 4 + kv) * T + t) * 128;
  dst[lane] = f2bits(bits2f(vsrc[lane]) + gate * vesrc[lane]);
  dst[lane + 64] = f2bits(bits2f(vsrc[lane + 64]) + gate * vesrc[lane + 64]);
}

// ---------------- V transpose: vp [bkv][t][d] -> vT [bkv][d][t] ----------------
// Block = (bkv, 64-token tile). LDS 16KB, granule-XOR swizzled rows of 64 keys.
__global__ __launch_bounds__(256) void v_transpose(const short* __restrict__ vp,
                                                   short* __restrict__ vT) {
  const int T = 2048;
  int bkv = blockIdx.x & 7;
  int t0 = (blockIdx.x >> 3) * 64;
  __shared__ __align__(16) short L[128 * 64];
  int tid = threadIdx.x;
  int tt = tid >> 2, dblk = tid & 3;
  const short* src = vp + ((size_t)bkv * T + t0 + tt) * 128 + dblk * 32;
  short8_t v0 = *(const short8_t*)(src);
  short8_t v1 = *(const short8_t*)(src + 8);
  short8_t v2 = *(const short8_t*)(src + 16);
  short8_t v3 = *(const short8_t*)(src + 24);
#pragma unroll
  for (int i = 0; i < 32; ++i) {
    int d = dblk * 32 + i;
    int byte = (d * 128 + tt * 2) ^ ((d & 7) << 4);
    short val = i < 8 ? v0[i] : i < 16 ? v1[i - 8] : i < 24 ? v2[i - 16] : v3[i - 24];
    *(short*)((char*)L + byte) = val;
  }
  __syncthreads();
  int d = tid >> 1, th = tid & 1;
  short* dst = vT + ((size_t)bkv * 128 + d) * T + t0 + th * 64;  // th*32 tokens *2B
  const char* Lp = (const char*)L;
#pragma unroll
  for (int g2 = 0; g2 < 4; ++g2) {
    short8_t o = *(const short8_t*)(Lp + ((d * 128 + th * 64 + g2 * 16) ^ ((d & 7) << 4)));
    *(short8_t*)(vT + ((size_t)bkv * 128 + d) * T + t0 + th * 32 + g2 * 8) = o;
  }
  (void)dst;
}

// ---------------- sliding-window flash attention v3 ----------------
// Swapped-QK 32x32, double-buffered K/V^T chunks via global_load_lds with
// counted vmcnt(8) (T3/T4). V^T pre-transposed in global (keys contiguous).
__global__ __launch_bounds__(256) void attn_sw3(const short* __restrict__ Q,
                                                const short* __restrict__ K,
                                                const short* __restrict__ VT,
                                                short* __restrict__ Y,
                                                const int* __restrict__ winp) {
  const int T = 2048, H = 16;
  const int win = *winp;
  int combo = blockIdx.x & 7;          // (b,kvh) -> XCD pin
  int j = blockIdx.x >> 3;
  int b = combo >> 2, kvh = combo & 3;
  int h = kvh * 4 + (j & 3);
  int q0 = (15 - (j >> 2)) * 128;      // heavy tiles first

  __shared__ __align__(16) short Ks[2][64 * 128];   // [key][d] swizzled granules
  __shared__ __align__(16) short Vs[2][128 * 64];   // [d][key] swizzled granules

  int tid = threadIdx.x, w = tid >> 6, lane = tid & 63;
  int ql = lane & 31, hi = lane >> 5;
  int qrow = q0 + w * 32 + ql;

  const short* qbase = Q + ((size_t)(b * H + h) * T + qrow) * 128;
  short8_t qf[8];
#pragma unroll
  for (int ks = 0; ks < 8; ++ks)
    qf[ks] = *reinterpret_cast<const short8_t*>(qbase + ks * 16 + hi * 8);

  const short* kbase = K + (size_t)(b * 4 + kvh) * T * 128;
  const short* vtbase = VT + (size_t)(b * 4 + kvh) * 128 * T;

  f32x16 acc[4];
#pragma unroll
  for (int dt = 0; dt < 4; ++dt)
#pragma unroll
    for (int r = 0; r < 16; ++r) acc[dt][r] = 0.f;
  float mreg = -1e30f, lsum = 0.f;

  int lo = q0 - win + 1;
  if (lo < 0) lo = 0;
  lo &= ~63;
  const int nt = (q0 + 128 - lo) >> 6;
  int qmin = q0 + w * 32, qmax = qmin + 31;

  // staging decode (per-lane global source for linear LDS dest):
  // K tile rows 256B=16 granules: krow = slot>>4, gc = (slot&15)^(krow&7)
  // VT tile rows 128B=8 granules: d = slot>>3, gc = (slot&7)^(d&7)
#define STAGE_A(ti, bi) do {                                                   \
    int kc_ = lo + (ti) * 64;                                                  \
    _Pragma("unroll")                                                          \
    for (int r = 0; r < 4; ++r) {                                              \
      int slot = (r * 4 + w) * 64 + lane;                                      \
      int krow = slot >> 4;                                                    \
      int gc = (slot & 15) ^ (krow & 7);                                       \
      GLD_LDS16(kbase + (size_t)(kc_ + krow) * 128 + gc * 8,                   \
                (char*)Ks[bi] + (r * 4 + w) * 1024);                           \
    }                                                                          \
    _Pragma("unroll")                                                          \
    for (int r = 0; r < 4; ++r) {                                              \
      int slot = (r * 4 + w) * 64 + lane;                                      \
      int d_ = slot >> 3;                                                      \
      int gc = (slot & 7) ^ (d_ & 7);                                          \
      GLD_LDS16(vtbase + (size_t)d_ * T + kc_ + gc * 8,                        \
                (char*)Vs[bi] + (r * 4 + w) * 1024);                           \
    }                                                                          \
  } while (0)

  STAGE_A(0, 0);

  int cur = 0;
  for (int t = 0; t < nt; ++t) {
    if (t + 1 < nt) {
      STAGE_A(t + 1, cur ^ 1);
      asm volatile("s_waitcnt vmcnt(8)" ::: "memory");  // tile t landed
    } else {
      asm volatile("s_waitcnt vmcnt(0)" ::: "memory");
    }
    asm volatile("s_barrier" ::: "memory");

    int kc = lo + t * 64;
    bool active = (kc <= qmax) && (kc + 63 >= qmin - win + 1);
    if (active) {
      const char* Kp = (const char*)Ks[cur];
      const char* Vp = (const char*)Vs[cur];
      // ---- S^T = K·Q^T ----
      f32x16 sA[2];
#pragma unroll
      for (int r = 0; r < 16; ++r) { sA[0][r] = 0.f; sA[1][r] = 0.f; }
#pragma unroll
      for (int kt = 0; kt < 2; ++kt) {
        int kr = kt * 32 + ql;
#pragma unroll
        for (int ks = 0; ks < 8; ++ks) {
          int byte = kr * 256 + (((ks * 2 + hi) ^ (kr & 7)) << 4);
          short8_t kf = *reinterpret_cast<const short8_t*>(Kp + byte);
          sA[kt] = MFMA32_BF16(kf, qf[ks], sA[kt]);
        }
      }
      // ---- mask + lane-local online softmax ----
      float pmax = -1e30f;
#pragma unroll
      for (int kt = 0; kt < 2; ++kt)
#pragma unroll
        for (int r = 0; r < 16; ++r) {
          int key = kc + kt * 32 + (r & 3) + 8 * (r >> 2) + 4 * hi;
          float sv = sA[kt][r];
          sv = ((unsigned)(qrow - key) < (unsigned)win) ? sv : -1e30f;
          sA[kt][r] = sv;
          pmax = fmaxf(pmax, sv);
        }
      pmax = fmaxf(pmax, __shfl_xor(pmax, 32, 64));
      float mn = fmaxf(mreg, pmax);
      float corr = exp2_(mreg - mn);
      mreg = mn;
      float rs = 0.f;
#pragma unroll
      for (int kt = 0; kt < 2; ++kt)
#pragma unroll
        for (int r = 0; r < 16; ++r) {
          float p = exp2_(sA[kt][r] - mn);
          sA[kt][r] = p;
          rs += p;
        }
      rs += __shfl_xor(rs, 32, 64);
      lsum = lsum * corr + rs;
#pragma unroll
      for (int dt = 0; dt < 4; ++dt)
#pragma unroll
        for (int r = 0; r < 16; ++r) acc[dt][r] *= corr;

      // ---- P^T exchange + PV: O^T += V^T · P^T ----
#pragma unroll
      for (int kt = 0; kt < 2; ++kt)
#pragma unroll
        for (int s = 0; s < 2; ++s) {
          unsigned a = pack2(sA[kt][8 * s + 0], sA[kt][8 * s + 1]);
          unsigned bb = pack2(sA[kt][8 * s + 2], sA[kt][8 * s + 3]);
          unsigned c = pack2(sA[kt][8 * s + 4], sA[kt][8 * s + 5]);
          unsigned dd = pack2(sA[kt][8 * s + 6], sA[kt][8 * s + 7]);
          unsigned sa = __shfl_xor(a, 32, 64);
          unsigned sb = __shfl_xor(bb, 32, 64);
          unsigned sc2 = __shfl_xor(c, 32, 64);
          unsigned sd = __shfl_xor(dd, 32, 64);
          union { unsigned u[4]; short8_t s8; } pu;
          pu.u[0] = hi ? sc2 : a;
          pu.u[1] = hi ? sd : bb;
          pu.u[2] = hi ? c : sa;
          pu.u[3] = hi ? dd : sb;
          const int kst = kt * 2 + s;
#pragma unroll
          for (int dt = 0; dt < 4; ++dt) {
            int d_ = dt * 32 + ql;
            int byte = (d_ << 7) + ((((kst * 2 + hi)) ^ (d_ & 7)) << 4);
            short8_t vf = *reinterpret_cast<const short8_t*>(Vp + byte);
            acc[dt] = MFMA32_BF16(vf, pu.s8, acc[dt]);
          }
        }
    }
    asm volatile("s_barrier" ::: "memory");
    cur ^= 1;
  }
#undef STAGE_A

  float rinv = 1.f / lsum;
  short* ybase = Y + ((size_t)(b * T + qrow) * H + h) * 128;
#pragma unroll
  for (int dt = 0; dt < 4; ++dt)
#pragma unroll
    for (int g2 = 0; g2 < 4; ++g2) {
      short4 o;
      o.x = f2bits(acc[dt][g2 * 4 + 0] * rinv);
      o.y = f2bits(acc[dt][g2 * 4 + 1] * rinv);
      o.z = f2bits(acc[dt][g2 * 4 + 2] * rinv);
      o.w = f2bits(acc[dt][g2 * 4 + 3] * rinv);
      *reinterpret_cast<short4*>(ybase + dt * 32 + 8 * g2 + 4 * hi) = o;
    }
}

// ---------------- launcher ----------------
extern "C" void kernel_launch(void* const* d_in, const int* in_sizes, int n_in,
                              void* d_out, int out_size, void* d_ws, size_t ws_size,
                              hipStream_t stream) {
  const float* x = (const float*)d_in[0];
  const float* ve = (const float*)d_in[1];
  const float* cosT = (const float*)d_in[2];
  const float* sinT = (const float*)d_in[3];
  const float* wq = (const float*)d_in[4];
  const float* wk = (const float*)d_in[5];
  const float* wv = (const float*)d_in[6];
  const float* wo = (const float*)d_in[7];
  const float* wgate = (const float*)d_in[8];
  const int* winp = (const int*)d_in[9];
  float* out = (float*)d_out;
  char* ws = (char*)d_ws;

  const int B = 2, T = 2048;
  short* xb    = (short*)(ws);
  short* wqkvb = (short*)(ws + 16777216);
  short* wob   = (short*)(ws + 29360128);
  short* qkv   = (short*)(ws + 37748736);
  short* qpost = (short*)(ws + 62914560);
  short* kpost = (short*)(ws + 79691776);
  short* vpost = (short*)(ws + 83886080);
  short* ybuf  = (short*)(ws + 88080384);
  short* vTb   = qkv;  // reuse qkv region after rope/v_gate consumed it (4 MB)

  cvt_f32_bf16<<<dim3(8192), 256, 0, stream>>>(x, xb, B * T * 2048);
  cvt_w3<<<dim3(6144), 256, 0, stream>>>(wq, wk, wv, wqkvb);
  cvt_f32_bf16<<<dim3(4096), 256, 0, stream>>>(wo, wob, 2048 * 2048);

  // QKV: M=4096 N=3072 K=2048 -> 32x24 = 768 blocks (%8==0)
  gemm_bt4<1><<<dim3(768), 256, 0, stream>>>(xb, wqkvb, qkv, 4096, 3072, 2048, 24);

  rope_rms_qk<<<dim3(B * T * 20 / 4), 256, 0, stream>>>(qkv, cosT, sinT, qpost, kpost);
  v_gate<<<dim3(B * T), 256, 0, stream>>>(qkv, x, ve, wgate, vpost);
  v_transpose<<<dim3(8 * (T / 64)), 256, 0, stream>>>(vpost, vTb);

  attn_sw3<<<dim3(512), 256, 0, stream>>>(qpost, kpost, vTb, ybuf, winp);

  // out-proj: M=4096 N=2048 K=2048 -> 32x16 = 512 blocks (%8==0)
  gemm_bt4<0><<<dim3(512), 256, 0, stream>>>(ybuf, wob, out, 4096, 2048, 2048, 16);
}